// Round 1
// baseline (332.388 us; speedup 1.0000x reference)
//
#include <hip/hip_runtime.h>
#include <hip/hip_bf16.h>
#include <math.h>

#define B_ 8
#define S_ 128
#define H_ 768
#define NH_ 12
#define HD_ 64
#define M_ 1024
#define KW_ 100
#define I_ 3072
#define QKVN 2304
#define NCHUNK 10
#define KWPER 10

typedef __attribute__((ext_vector_type(8))) short short8;
typedef __attribute__((ext_vector_type(8))) unsigned short ushort8;
typedef __attribute__((ext_vector_type(4))) float f32x4;

static __device__ __forceinline__ unsigned short f2b(float f) {
  union { float f; unsigned int u; } v; v.f = f;
  return (unsigned short)((v.u + 0x7fffu + ((v.u >> 16) & 1u)) >> 16);
}
static __device__ __forceinline__ float b2f(unsigned short b) {
  union { unsigned int u; float f; } v; v.u = ((unsigned int)b) << 16;
  return v.f;
}

// ---------------- prep kernels ----------------

__global__ void k_f32_to_bf16(const float* __restrict__ src, unsigned short* __restrict__ dst, int n) {
  int i = (blockIdx.x * 256 + threadIdx.x) * 4;
  if (i + 3 < n) {
    float4 v = *(const float4*)&src[i];
    uint2 o;
    o.x = (unsigned)f2b(v.x) | ((unsigned)f2b(v.y) << 16);
    o.y = (unsigned)f2b(v.z) | ((unsigned)f2b(v.w) << 16);
    *(uint2*)&dst[i] = o;
  }
}

// dst[c*R + r] = bf16(src[r*C + c]);  grid (C/32, R/32), 256 threads
__global__ void k_transpose_bf16(const float* __restrict__ src, unsigned short* __restrict__ dst,
                                 int R, int C) {
  __shared__ float tile[32][33];
  int tx = threadIdx.x & 31, ty = threadIdx.x >> 5;
  int c0 = blockIdx.x * 32, r0 = blockIdx.y * 32;
#pragma unroll
  for (int i = 0; i < 4; i++)
    tile[ty + i * 8][tx] = src[(size_t)(r0 + ty + i * 8) * C + c0 + tx];
  __syncthreads();
#pragma unroll
  for (int i = 0; i < 4; i++)
    dst[(size_t)(c0 + ty + i * 8) * R + r0 + tx] = f2b(tile[tx][ty + i * 8]);
}

__global__ void k_prep_kw(const float* __restrict__ pos, const float* __restrict__ neg,
                          const float* __restrict__ Wmlp,
                          float* __restrict__ kw2s, float* __restrict__ kwm) {
  int idx = blockIdx.x * 256 + threadIdx.x;
  if (idx >= KW_ * H_) return;
  int j = idx / H_, d = idx - j * H_;
  float v = (j & 1) ? neg[(j >> 1) * H_ + d] : pos[(j >> 1) * H_ + d];
  kw2s[idx] = v * v * 0.125f;   // kw^2 * (1/sqrt(64))
  kwm[idx]  = v * Wmlp[j];
}

__global__ void k_prep_c0(const float* __restrict__ Wmlp, const float* __restrict__ bmlp,
                          const float* __restrict__ bo, float* __restrict__ c0) {
  __shared__ float red[256];
  int t = threadIdx.x;
  red[t] = (t < KW_) ? Wmlp[t] : 0.f;
  __syncthreads();
  for (int s = 128; s > 0; s >>= 1) { if (t < s) red[t] += red[t + s]; __syncthreads(); }
  float sWm = red[0];
  for (int n = t; n < H_; n += 256) c0[n] = sWm * bo[n] + bmlp[0];
}

// ---------------- bf16 MFMA GEMM, B^T layout ----------------
// C[M,N] = A[M,K] @ BT[N,K]^T ; 128x128 tile, 4 waves of 64x64.
// EPI: 0 -> outB = bf16(C)
//      1 -> t = C + bias[col]; outF = t; outB = bf16(t)
//      2 -> t = C + bias[col]; outB = bf16(gelu_exact(t))
//      3 -> t = C + bias[col] + res[row*N+col]; outF = t
template <int EPI>
__launch_bounds__(256)
__global__ void k_gemm_bt(const unsigned short* __restrict__ A, const unsigned short* __restrict__ BT,
                          int M, int N, int K,
                          float* __restrict__ outF, unsigned short* __restrict__ outB,
                          const float* __restrict__ bias, const float* __restrict__ res) {
  __shared__ unsigned short Asm[128][56];
  __shared__ unsigned short Bsm[128][56];
  int tid = threadIdx.x;
  int lane = tid & 63, wid = tid >> 6;
  int g = lane >> 4, c16 = lane & 15;
  int wr = wid >> 1, wc = wid & 1;
  int m0 = blockIdx.y * 128, n0 = blockIdx.x * 128;
  f32x4 acc[4][4] = {};
  int r = tid >> 1, half = (tid & 1) * 16;
  const unsigned short* Ap = A + (size_t)(m0 + r) * K + half;
  const unsigned short* Bp = BT + (size_t)(n0 + r) * K + half;
  for (int kt = 0; kt < K; kt += 32) {
    __syncthreads();
    ushort8 a0 = *(const ushort8*)(Ap + kt);
    ushort8 a1 = *(const ushort8*)(Ap + kt + 8);
    ushort8 b0 = *(const ushort8*)(Bp + kt);
    ushort8 b1 = *(const ushort8*)(Bp + kt + 8);
    *(ushort8*)&Asm[r][half] = a0;  *(ushort8*)&Asm[r][half + 8] = a1;
    *(ushort8*)&Bsm[r][half] = b0;  *(ushort8*)&Bsm[r][half + 8] = b1;
    __syncthreads();
    short8 af[4], bf[4];
#pragma unroll
    for (int mi = 0; mi < 4; mi++) af[mi] = *(const short8*)&Asm[wr * 64 + mi * 16 + c16][g * 8];
#pragma unroll
    for (int ni = 0; ni < 4; ni++) bf[ni] = *(const short8*)&Bsm[wc * 64 + ni * 16 + c16][g * 8];
#pragma unroll
    for (int mi = 0; mi < 4; mi++)
#pragma unroll
      for (int ni = 0; ni < 4; ni++)
        acc[mi][ni] = __builtin_amdgcn_mfma_f32_16x16x32_bf16(af[mi], bf[ni], acc[mi][ni], 0, 0, 0);
  }
#pragma unroll
  for (int mi = 0; mi < 4; mi++)
#pragma unroll
    for (int ni = 0; ni < 4; ni++)
#pragma unroll
      for (int rr = 0; rr < 4; rr++) {
        int row = m0 + wr * 64 + mi * 16 + g * 4 + rr;
        int col = n0 + wc * 64 + ni * 16 + c16;
        float v = acc[mi][ni][rr];
        if (EPI == 0) {
          outB[(size_t)row * N + col] = f2b(v);
        } else if (EPI == 1) {
          float t = v + bias[col];
          outF[(size_t)row * N + col] = t;
          outB[(size_t)row * N + col] = f2b(t);
        } else if (EPI == 2) {
          float t = v + bias[col];
          float gl = 0.5f * t * (1.f + erff(t * 0.70710678118f));
          outB[(size_t)row * N + col] = f2b(gl);
        } else {
          float t = v + bias[col] + res[(size_t)row * N + col];
          outF[(size_t)row * N + col] = t;
        }
      }
}

// ---------------- fused keyword attention ----------------
// grid (NCHUNK, NH_, B_), 512 threads (8 waves).
// Per block: loop 10 keywords; scores = (PQ*kw2*scale) @ PK^T (+mask), column-softmax
// over q, ctx = w @ PV, acc += ctx * (kw[d]*Wmlp[k]). Writes f32 partial per chunk.
__launch_bounds__(512)
__global__ void k_attn(const unsigned short* __restrict__ PQKV, const float* __restrict__ mask,
                       const float* __restrict__ kw2s, const float* __restrict__ kwm,
                       float* __restrict__ partial) {
  __shared__ unsigned short PK[128][72];
  __shared__ unsigned short PVT[64][136];
  __shared__ unsigned short AS[128][72];
  __shared__ unsigned short WL[128][136];
  int tid = threadIdx.x;
  int lane = tid & 63, wid = tid >> 6;
  int g = lane >> 4, c16 = lane & 15;
  int chunk = blockIdx.x, h = blockIdx.y, b = blockIdx.z;
  const size_t rowbase = (size_t)b * 128 * QKVN;
  int kq = tid >> 2, quarter = tid & 3;
  {
    const unsigned short* srck = PQKV + rowbase + (size_t)kq * QKVN + H_ + h * HD_ + quarter * 16;
    ushort8 v0 = *(const ushort8*)srck;
    ushort8 v1 = *(const ushort8*)(srck + 8);
    *(ushort8*)&PK[kq][quarter * 16] = v0;
    *(ushort8*)&PK[kq][quarter * 16 + 8] = v1;
    const unsigned short* srcv = PQKV + rowbase + (size_t)kq * QKVN + 2 * H_ + h * HD_ + quarter * 16;
    ushort8 w0 = *(const ushort8*)srcv;
    ushort8 w1 = *(const ushort8*)(srcv + 8);
#pragma unroll
    for (int j = 0; j < 8; j++) PVT[quarter * 16 + j][kq] = w0[j];
#pragma unroll
    for (int j = 0; j < 8; j++) PVT[quarter * 16 + 8 + j][kq] = w1[j];
  }
  __syncthreads();
  float mval = mask[b * S_ + wid * 16 + c16];  // constant along q: cancels in softmax, kept for fidelity
  float accO[4][4] = {};
  for (int ki = 0; ki < KWPER; ki++) {
    int kwi = chunk * KWPER + ki;
    // A0: AS[q][d] = bf16( PQ[q,d] * kw^2 * scale )
    {
      const unsigned short* srcq = PQKV + rowbase + (size_t)kq * QKVN + h * HD_ + quarter * 16;
      ushort8 q0 = *(const ushort8*)srcq;
      ushort8 q1 = *(const ushort8*)(srcq + 8);
      const float* kp = kw2s + (size_t)kwi * H_ + h * HD_ + quarter * 16;
      short8 o0, o1;
#pragma unroll
      for (int j = 0; j < 8; j++) o0[j] = (short)f2b(b2f(q0[j]) * kp[j]);
#pragma unroll
      for (int j = 0; j < 8; j++) o1[j] = (short)f2b(b2f(q1[j]) * kp[j + 8]);
      *(short8*)&AS[kq][quarter * 16] = o0;
      *(short8*)&AS[kq][quarter * 16 + 8] = o1;
    }
    __syncthreads();
    // Phase A: wave wid owns key-columns wid*16 + c16 ; all 128 q rows
    short8 bk0 = *(const short8*)&PK[wid * 16 + c16][g * 8];
    short8 bk1 = *(const short8*)&PK[wid * 16 + c16][32 + g * 8];
    f32x4 sc[8];
#pragma unroll
    for (int mi = 0; mi < 8; mi++) {
      short8 aq0 = *(const short8*)&AS[mi * 16 + c16][g * 8];
      short8 aq1 = *(const short8*)&AS[mi * 16 + c16][32 + g * 8];
      f32x4 z = {0.f, 0.f, 0.f, 0.f};
      z = __builtin_amdgcn_mfma_f32_16x16x32_bf16(aq0, bk0, z, 0, 0, 0);
      z = __builtin_amdgcn_mfma_f32_16x16x32_bf16(aq1, bk1, z, 0, 0, 0);
      sc[mi] = z;
    }
    // column softmax over q (per lane: 32 values; then butterfly over lanes ^16, ^32)
    float mx = -1e30f;
#pragma unroll
    for (int mi = 0; mi < 8; mi++)
#pragma unroll
      for (int rr = 0; rr < 4; rr++) { float v = sc[mi][rr] + mval; sc[mi][rr] = v; mx = fmaxf(mx, v); }
    mx = fmaxf(mx, __shfl_xor(mx, 16));
    mx = fmaxf(mx, __shfl_xor(mx, 32));
    float sm = 0.f;
#pragma unroll
    for (int mi = 0; mi < 8; mi++)
#pragma unroll
      for (int rr = 0; rr < 4; rr++) { float e = __expf(sc[mi][rr] - mx); sc[mi][rr] = e; sm += e; }
    sm += __shfl_xor(sm, 16);
    sm += __shfl_xor(sm, 32);
    float rinv = 1.0f / sm;
    int kcol = wid * 16 + c16;
#pragma unroll
    for (int mi = 0; mi < 8; mi++)
#pragma unroll
      for (int rr = 0; rr < 4; rr++)
        WL[mi * 16 + g * 4 + rr][kcol] = f2b(sc[mi][rr] * rinv);
    __syncthreads();
    // Phase C: wave wid owns q-tile wid; ctx = w @ PV, accumulate * kw[d]*Wmlp[kwi]
    short8 wf[4];
#pragma unroll
    for (int kc = 0; kc < 4; kc++) wf[kc] = *(const short8*)&WL[wid * 16 + c16][kc * 32 + g * 8];
#pragma unroll
    for (int ni = 0; ni < 4; ni++) {
      f32x4 z = {0.f, 0.f, 0.f, 0.f};
#pragma unroll
      for (int kc = 0; kc < 4; kc++) {
        short8 vf = *(const short8*)&PVT[ni * 16 + c16][kc * 32 + g * 8];
        z = __builtin_amdgcn_mfma_f32_16x16x32_bf16(wf[kc], vf, z, 0, 0, 0);
      }
      float km = kwm[(size_t)kwi * H_ + h * HD_ + ni * 16 + c16];
#pragma unroll
      for (int rr = 0; rr < 4; rr++) accO[ni][rr] += z[rr] * km;
    }
    __syncthreads();
  }
  float* dst = partial + (size_t)chunk * M_ * H_;
#pragma unroll
  for (int ni = 0; ni < 4; ni++)
#pragma unroll
    for (int rr = 0; rr < 4; rr++) {
      int q = wid * 16 + g * 4 + rr;
      dst[(size_t)(b * 128 + q) * H_ + h * HD_ + ni * 16 + c16] = accO[ni][rr];
    }
}

__global__ void k_reduce(const float* __restrict__ partial, unsigned short* __restrict__ ctxsum) {
  int i = (blockIdx.x * 256 + threadIdx.x) * 4;
  float4 s = *(const float4*)&partial[i];
#pragma unroll
  for (int c = 1; c < NCHUNK; c++) {
    float4 v = *(const float4*)&partial[(size_t)c * M_ * H_ + i];
    s.x += v.x; s.y += v.y; s.z += v.z; s.w += v.w;
  }
  uint2 o;
  o.x = (unsigned)f2b(s.x) | ((unsigned)f2b(s.y) << 16);
  o.y = (unsigned)f2b(s.z) | ((unsigned)f2b(s.w) << 16);
  *(uint2*)&ctxsum[i] = o;
}

__launch_bounds__(256)
__global__ void k_ln(const float* __restrict__ x, const float* __restrict__ gamma,
                     const float* __restrict__ beta, float* __restrict__ out) {
  __shared__ float red[8];
  int row = blockIdx.x, t = threadIdx.x;
  int lane = t & 63, wid = t >> 6;
  const float* xr = x + (size_t)row * H_;
  float v[3];
#pragma unroll
  for (int j = 0; j < 3; j++) v[j] = xr[t + j * 256];
  float s = v[0] + v[1] + v[2];
#pragma unroll
  for (int off = 1; off < 64; off <<= 1) s += __shfl_xor(s, off);
  if (lane == 0) red[wid] = s;
  __syncthreads();
  float mu = (red[0] + red[1] + red[2] + red[3]) * (1.f / 768.f);
  float q = 0.f;
#pragma unroll
  for (int j = 0; j < 3; j++) { float d = v[j] - mu; q += d * d; }
#pragma unroll
  for (int off = 1; off < 64; off <<= 1) q += __shfl_xor(q, off);
  if (lane == 0) red[4 + wid] = q;
  __syncthreads();
  float var = (red[4] + red[5] + red[6] + red[7]) * (1.f / 768.f);
  float rstd = rsqrtf(var + 1e-12f);
#pragma unroll
  for (int j = 0; j < 3; j++) {
    int c = t + j * 256;
    out[(size_t)row * H_ + c] = gamma[c] * ((v[j] - mu) * rstd) + beta[c];
  }
}

// ---------------- launch ----------------

extern "C" void kernel_launch(void* const* d_in, const int* in_sizes, int n_in,
                              void* d_out, int out_size, void* d_ws, size_t ws_size,
                              hipStream_t stream) {
  const float* hidden = (const float*)d_in[0];
  const float* posk   = (const float*)d_in[1];
  const float* negk   = (const float*)d_in[2];
  const float* mask   = (const float*)d_in[3];
  const float* Wq     = (const float*)d_in[4];
  const float* Wk     = (const float*)d_in[5];
  const float* Wv     = (const float*)d_in[6];
  const float* Wo     = (const float*)d_in[7];
  const float* bo     = (const float*)d_in[8];
  const float* Wmlp   = (const float*)d_in[9];
  const float* bmlp   = (const float*)d_in[10];
  const float* Wdown  = (const float*)d_in[11];
  const float* bdown  = (const float*)d_in[12];
  const float* Wup    = (const float*)d_in[13];
  const float* bup    = (const float*)d_in[14];
  const float* gamma  = (const float*)d_in[15];
  const float* beta   = (const float*)d_in[16];

  char* ws = (char*)d_ws;
  size_t off = 0;
  auto alloc = [&](size_t bytes) -> void* {
    void* p = ws + off;
    off += (bytes + 255) & ~(size_t)255;
    return p;
  };
  unsigned short* hb     = (unsigned short*)alloc((size_t)M_ * H_ * 2);
  unsigned short* qkvT   = (unsigned short*)alloc((size_t)QKVN * H_ * 2);
  unsigned short* WoT    = (unsigned short*)alloc((size_t)H_ * H_ * 2);
  unsigned short* WdownT = (unsigned short*)alloc((size_t)I_ * H_ * 2);
  unsigned short* WupT   = (unsigned short*)alloc((size_t)H_ * I_ * 2);
  unsigned short* PQKV   = (unsigned short*)alloc((size_t)M_ * QKVN * 2);
  float* kw2s    = (float*)alloc((size_t)KW_ * H_ * 4);
  float* kwm     = (float*)alloc((size_t)KW_ * H_ * 4);
  float* c0      = (float*)alloc((size_t)H_ * 4);
  float* partial = (float*)alloc((size_t)NCHUNK * M_ * H_ * 4);
  unsigned short* ctxsum = (unsigned short*)alloc((size_t)M_ * H_ * 2);
  float* fusedF  = (float*)alloc((size_t)M_ * H_ * 4);
  unsigned short* fusedB = (unsigned short*)alloc((size_t)M_ * H_ * 2);
  unsigned short* downB  = (unsigned short*)alloc((size_t)M_ * I_ * 2);
  float* xF      = (float*)alloc((size_t)M_ * H_ * 4);

  k_f32_to_bf16<<<768, 256, 0, stream>>>(hidden, hb, M_ * H_);
  k_transpose_bf16<<<dim3(24, 24), 256, 0, stream>>>(Wq, qkvT, 768, 768);
  k_transpose_bf16<<<dim3(24, 24), 256, 0, stream>>>(Wk, qkvT + 768 * 768, 768, 768);
  k_transpose_bf16<<<dim3(24, 24), 256, 0, stream>>>(Wv, qkvT + 2 * 768 * 768, 768, 768);
  k_transpose_bf16<<<dim3(24, 24), 256, 0, stream>>>(Wo, WoT, 768, 768);
  k_transpose_bf16<<<dim3(96, 24), 256, 0, stream>>>(Wdown, WdownT, 768, 3072);
  k_transpose_bf16<<<dim3(24, 96), 256, 0, stream>>>(Wup, WupT, 3072, 768);
  k_prep_kw<<<300, 256, 0, stream>>>(posk, negk, Wmlp, kw2s, kwm);
  k_prep_c0<<<1, 256, 0, stream>>>(Wmlp, bmlp, bo, c0);

  k_gemm_bt<0><<<dim3(18, 8), 256, 0, stream>>>(hb, qkvT, M_, QKVN, H_, nullptr, PQKV, nullptr, nullptr);
  k_attn<<<dim3(NCHUNK, NH_, B_), 512, 0, stream>>>(PQKV, mask, kw2s, kwm, partial);
  k_reduce<<<768, 256, 0, stream>>>(partial, ctxsum);
  k_gemm_bt<1><<<dim3(6, 8), 256, 0, stream>>>(ctxsum, WoT, M_, H_, H_, fusedF, fusedB, c0, nullptr);
  k_gemm_bt<2><<<dim3(24, 8), 256, 0, stream>>>(fusedB, WdownT, M_, I_, H_, nullptr, downB, bdown, nullptr);
  k_gemm_bt<3><<<dim3(6, 8), 256, 0, stream>>>(downB, WupT, M_, H_, I_, xF, nullptr, bup, fusedF);
  k_ln<<<M_, 256, 0, stream>>>(xF, gamma, beta, (float*)d_out);
}

// Round 2
// 290.380 us; speedup vs baseline: 1.1447x; 1.1447x over previous
//
#include <hip/hip_runtime.h>
#include <hip/hip_bf16.h>
#include <math.h>

#define B_ 8
#define S_ 128
#define H_ 768
#define NH_ 12
#define HD_ 64
#define M_ 1024
#define KW_ 100
#define I_ 3072
#define QKVN 2304
#define NCHUNK 10
#define KWPER 10
#define LOG2E 1.4426950408889634f

typedef __attribute__((ext_vector_type(8))) short short8;
typedef __attribute__((ext_vector_type(8))) unsigned short ushort8;
typedef __attribute__((ext_vector_type(4))) float f32x4;

static __device__ __forceinline__ unsigned short f2b(float f) {
  union { float f; unsigned int u; } v; v.f = f;
  return (unsigned short)((v.u + 0x7fffu + ((v.u >> 16) & 1u)) >> 16);
}
static __device__ __forceinline__ float b2f(unsigned short b) {
  union { unsigned int u; float f; } v; v.u = ((unsigned int)b) << 16;
  return v.f;
}

// ---------------- prep kernels ----------------

__global__ void k_f32_to_bf16(const float* __restrict__ src, unsigned short* __restrict__ dst, int n) {
  int i = (blockIdx.x * 256 + threadIdx.x) * 4;
  if (i + 3 < n) {
    float4 v = *(const float4*)&src[i];
    uint2 o;
    o.x = (unsigned)f2b(v.x) | ((unsigned)f2b(v.y) << 16);
    o.y = (unsigned)f2b(v.z) | ((unsigned)f2b(v.w) << 16);
    *(uint2*)&dst[i] = o;
  }
}

// dst[c*R + r] = bf16(src[r*C + c]);  grid (C/32, R/32), 256 threads
__global__ void k_transpose_bf16(const float* __restrict__ src, unsigned short* __restrict__ dst,
                                 int R, int C) {
  __shared__ float tile[32][33];
  int tx = threadIdx.x & 31, ty = threadIdx.x >> 5;
  int c0 = blockIdx.x * 32, r0 = blockIdx.y * 32;
#pragma unroll
  for (int i = 0; i < 4; i++)
    tile[ty + i * 8][tx] = src[(size_t)(r0 + ty + i * 8) * C + c0 + tx];
  __syncthreads();
#pragma unroll
  for (int i = 0; i < 4; i++)
    dst[(size_t)(c0 + ty + i * 8) * R + r0 + tx] = f2b(tile[tx][ty + i * 8]);
}

__global__ void k_prep_kw(const float* __restrict__ pos, const float* __restrict__ neg,
                          const float* __restrict__ Wmlp,
                          float* __restrict__ kw2s, float* __restrict__ kwm) {
  int idx = blockIdx.x * 256 + threadIdx.x;
  if (idx >= KW_ * H_) return;
  int j = idx / H_, d = idx - j * H_;
  float v = (j & 1) ? neg[(j >> 1) * H_ + d] : pos[(j >> 1) * H_ + d];
  kw2s[idx] = v * v * 0.125f * LOG2E;   // kw^2 * (1/sqrt(64)) * log2(e)  (exp2-based softmax)
  kwm[idx]  = v * Wmlp[j];
}

__global__ void k_prep_c0(const float* __restrict__ Wmlp, const float* __restrict__ bmlp,
                          const float* __restrict__ bo, float* __restrict__ c0) {
  __shared__ float red[256];
  int t = threadIdx.x;
  red[t] = (t < KW_) ? Wmlp[t] : 0.f;
  __syncthreads();
  for (int s = 128; s > 0; s >>= 1) { if (t < s) red[t] += red[t + s]; __syncthreads(); }
  float sWm = red[0];
  for (int n = t; n < H_; n += 256) c0[n] = sWm * bo[n] + bmlp[0];
}

// ---------------- bf16 MFMA GEMM, B^T layout ----------------
template <int EPI>
__launch_bounds__(256)
__global__ void k_gemm_bt(const unsigned short* __restrict__ A, const unsigned short* __restrict__ BT,
                          int M, int N, int K,
                          float* __restrict__ outF, unsigned short* __restrict__ outB,
                          const float* __restrict__ bias, const float* __restrict__ res) {
  __shared__ unsigned short Asm[128][56];
  __shared__ unsigned short Bsm[128][56];
  int tid = threadIdx.x;
  int lane = tid & 63, wid = tid >> 6;
  int g = lane >> 4, c16 = lane & 15;
  int wr = wid >> 1, wc = wid & 1;
  int m0 = blockIdx.y * 128, n0 = blockIdx.x * 128;
  f32x4 acc[4][4] = {};
  int r = tid >> 1, half = (tid & 1) * 16;
  const unsigned short* Ap = A + (size_t)(m0 + r) * K + half;
  const unsigned short* Bp = BT + (size_t)(n0 + r) * K + half;
  for (int kt = 0; kt < K; kt += 32) {
    __syncthreads();
    ushort8 a0 = *(const ushort8*)(Ap + kt);
    ushort8 a1 = *(const ushort8*)(Ap + kt + 8);
    ushort8 b0 = *(const ushort8*)(Bp + kt);
    ushort8 b1 = *(const ushort8*)(Bp + kt + 8);
    *(ushort8*)&Asm[r][half] = a0;  *(ushort8*)&Asm[r][half + 8] = a1;
    *(ushort8*)&Bsm[r][half] = b0;  *(ushort8*)&Bsm[r][half + 8] = b1;
    __syncthreads();
    short8 af[4], bf[4];
#pragma unroll
    for (int mi = 0; mi < 4; mi++) af[mi] = *(const short8*)&Asm[wr * 64 + mi * 16 + c16][g * 8];
#pragma unroll
    for (int ni = 0; ni < 4; ni++) bf[ni] = *(const short8*)&Bsm[wc * 64 + ni * 16 + c16][g * 8];
#pragma unroll
    for (int mi = 0; mi < 4; mi++)
#pragma unroll
      for (int ni = 0; ni < 4; ni++)
        acc[mi][ni] = __builtin_amdgcn_mfma_f32_16x16x32_bf16(af[mi], bf[ni], acc[mi][ni], 0, 0, 0);
  }
#pragma unroll
  for (int mi = 0; mi < 4; mi++)
#pragma unroll
    for (int ni = 0; ni < 4; ni++)
#pragma unroll
      for (int rr = 0; rr < 4; rr++) {
        int row = m0 + wr * 64 + mi * 16 + g * 4 + rr;
        int col = n0 + wc * 64 + ni * 16 + c16;
        float v = acc[mi][ni][rr];
        if (EPI == 0) {
          outB[(size_t)row * N + col] = f2b(v);
        } else if (EPI == 1) {
          float t = v + bias[col];
          outF[(size_t)row * N + col] = t;
          outB[(size_t)row * N + col] = f2b(t);
        } else if (EPI == 2) {
          float t = v + bias[col];
          float gl = 0.5f * t * (1.f + erff(t * 0.70710678118f));
          outB[(size_t)row * N + col] = f2b(gl);
        } else {
          float t = v + bias[col] + res[(size_t)row * N + col];
          outF[(size_t)row * N + col] = t;
        }
      }
}

// ---------------- fused keyword attention (v2) ----------------
// grid (NCHUNK, NH_, B_), 512 threads (8 waves), 2 blocks/CU.
// LDS: WLAS (32KB) holds AS [128][64] (swzA) during QK, then WL [128][128] (swzW)
//      for the softmaxed weights; PK [128][64] swzA; PVT padded; kw stage.

// swizzled ushort index, 128-byte rows: byte = r*128 + c*2, XOR (r&7)<<4
static __device__ __forceinline__ int swzA(int r, int c) {
  return (((r << 7) + (c << 1)) ^ ((r & 7) << 4)) >> 1;
}
// swizzled ushort index, 256-byte rows: XOR ((r>>1)&7)<<4
static __device__ __forceinline__ int swzW(int r, int c) {
  return (((r << 8) + (c << 1)) ^ (((r >> 1) & 7) << 4)) >> 1;
}

__launch_bounds__(512, 4)
__global__ void k_attn(const unsigned short* __restrict__ PQKV, const float* __restrict__ mask,
                       const float* __restrict__ kw2s, const float* __restrict__ kwm,
                       float* __restrict__ partial) {
  __shared__ unsigned short WLAS[128 * 128];   // 32KB: AS (first 16KB, swzA) / WL (swzW)
  __shared__ unsigned short PKs[128 * 64];     // 16KB, swzA
  __shared__ unsigned short PVT[64][136];      // 17KB, padded
  __shared__ float kwst[2 * KWPER * 64];       // 5KB: [0]=kw2*scale*log2e, [1]=kw*Wmlp
  int tid = threadIdx.x;
  int lane = tid & 63, wid = tid >> 6;
  int g = lane >> 4, c16 = lane & 15;
  int chunk = blockIdx.x, h = blockIdx.y, b = blockIdx.z;
  const size_t rowbase = (size_t)b * 128 * QKVN;
  int kq = tid >> 2, quarter = tid & 3;
  // ---- prologue: stage K (swzA), V^T (padded), Q row in regs, kw tables ----
  ushort8 q0, q1;
  {
    const unsigned short* srck = PQKV + rowbase + (size_t)kq * QKVN + H_ + h * HD_ + quarter * 16;
    ushort8 v0 = *(const ushort8*)srck;
    ushort8 v1 = *(const ushort8*)(srck + 8);
    *(ushort8*)&PKs[swzA(kq, quarter * 16)] = v0;
    *(ushort8*)&PKs[swzA(kq, quarter * 16 + 8)] = v1;
    const unsigned short* srcv = PQKV + rowbase + (size_t)kq * QKVN + 2 * H_ + h * HD_ + quarter * 16;
    ushort8 w0 = *(const ushort8*)srcv;
    ushort8 w1 = *(const ushort8*)(srcv + 8);
#pragma unroll
    for (int j = 0; j < 8; j++) PVT[quarter * 16 + j][kq] = w0[j];
#pragma unroll
    for (int j = 0; j < 8; j++) PVT[quarter * 16 + 8 + j][kq] = w1[j];
    const unsigned short* srcq = PQKV + rowbase + (size_t)kq * QKVN + h * HD_ + quarter * 16;
    q0 = *(const ushort8*)srcq;
    q1 = *(const ushort8*)(srcq + 8);
    for (int i = tid; i < 2 * KWPER * 64; i += 512) {
      int half = i >= KWPER * 64;
      int i2 = i - half * KWPER * 64;
      int ki = i2 >> 6, d = i2 & 63;
      const float* src = half ? kwm : kw2s;
      kwst[i] = src[(size_t)(chunk * KWPER + ki) * H_ + h * HD_ + d];
    }
  }
  __syncthreads();
  float mval = mask[b * S_ + wid * 16 + c16] * LOG2E;  // constant along q (softmax axis)
  int kcol = wid * 16 + c16;
  float accO[4][4] = {};
  for (int ki = 0; ki < KWPER; ki++) {
    // ---- build AS[q][d] = bf16( PQ[q,d] * kw^2 * scale * log2e ) into WLAS (swzA) ----
    {
      const float* kp = &kwst[ki * 64 + quarter * 16];
      unsigned int o[8];
#pragma unroll
      for (int p = 0; p < 4; p++) {
        float lo = b2f(q0[2 * p]) * kp[2 * p];
        float hi = b2f(q0[2 * p + 1]) * kp[2 * p + 1];
        asm("v_cvt_pk_bf16_f32 %0, %1, %2" : "=v"(o[p]) : "v"(lo), "v"(hi));
      }
#pragma unroll
      for (int p = 0; p < 4; p++) {
        float lo = b2f(q1[2 * p]) * kp[8 + 2 * p];
        float hi = b2f(q1[2 * p + 1]) * kp[8 + 2 * p + 1];
        asm("v_cvt_pk_bf16_f32 %0, %1, %2" : "=v"(o[4 + p]) : "v"(lo), "v"(hi));
      }
      *(uint4*)&WLAS[swzA(kq, quarter * 16)] = *(const uint4*)&o[0];
      *(uint4*)&WLAS[swzA(kq, quarter * 16 + 8)] = *(const uint4*)&o[4];
    }
    __syncthreads();
    // ---- QK^T: wave owns key-columns kcol; all 128 q rows ----
    short8 bk0 = *(const short8*)&PKs[swzA(kcol, g * 8)];
    short8 bk1 = *(const short8*)&PKs[swzA(kcol, 32 + g * 8)];
    f32x4 sc[8];
    __builtin_amdgcn_s_setprio(1);
#pragma unroll
    for (int mi = 0; mi < 8; mi++) {
      short8 aq0 = *(const short8*)&WLAS[swzA(mi * 16 + c16, g * 8)];
      short8 aq1 = *(const short8*)&WLAS[swzA(mi * 16 + c16, 32 + g * 8)];
      f32x4 z = {0.f, 0.f, 0.f, 0.f};
      z = __builtin_amdgcn_mfma_f32_16x16x32_bf16(aq0, bk0, z, 0, 0, 0);
      z = __builtin_amdgcn_mfma_f32_16x16x32_bf16(aq1, bk1, z, 0, 0, 0);
      sc[mi] = z;
    }
    __builtin_amdgcn_s_setprio(0);
    // ---- column softmax over q (32 reg values + lanes ^16, ^32), exp2-based ----
    float mx = -1e30f;
#pragma unroll
    for (int mi = 0; mi < 8; mi++)
#pragma unroll
      for (int rr = 0; rr < 4; rr++) { float v = sc[mi][rr] + mval; sc[mi][rr] = v; mx = fmaxf(mx, v); }
    mx = fmaxf(mx, __shfl_xor(mx, 16));
    mx = fmaxf(mx, __shfl_xor(mx, 32));
    float sm = 0.f;
#pragma unroll
    for (int mi = 0; mi < 8; mi++)
#pragma unroll
      for (int rr = 0; rr < 4; rr++) { float e = __builtin_amdgcn_exp2f(sc[mi][rr] - mx); sc[mi][rr] = e; sm += e; }
    sm += __shfl_xor(sm, 16);
    sm += __shfl_xor(sm, 32);
    float rinv = 1.0f / sm;
    __syncthreads();  // AS reads done before overwriting region as WL
    // ---- write normalized weights WL[q][k] (swzW) ----
#pragma unroll
    for (int mi = 0; mi < 8; mi++) {
      float a0 = sc[mi][0] * rinv, a1 = sc[mi][1] * rinv;
      float a2 = sc[mi][2] * rinv, a3 = sc[mi][3] * rinv;
      unsigned int pk0, pk1;
      asm("v_cvt_pk_bf16_f32 %0, %1, %2" : "=v"(pk0) : "v"(a0), "v"(a1));
      asm("v_cvt_pk_bf16_f32 %0, %1, %2" : "=v"(pk1) : "v"(a2), "v"(a3));
      int rbase = mi * 16 + g * 4;
      WLAS[swzW(rbase + 0, kcol)] = (unsigned short)(pk0 & 0xffffu);
      WLAS[swzW(rbase + 1, kcol)] = (unsigned short)(pk0 >> 16);
      WLAS[swzW(rbase + 2, kcol)] = (unsigned short)(pk1 & 0xffffu);
      WLAS[swzW(rbase + 3, kcol)] = (unsigned short)(pk1 >> 16);
    }
    __syncthreads();
    // ---- PV: wave owns q-tile wid; ctx = w @ PV, accumulate * kw[d]*Wmlp[kwi] ----
    short8 wf[4];
#pragma unroll
    for (int kc = 0; kc < 4; kc++) wf[kc] = *(const short8*)&WLAS[swzW(wid * 16 + c16, kc * 32 + g * 8)];
    __builtin_amdgcn_s_setprio(1);
    f32x4 zz[4];
#pragma unroll
    for (int ni = 0; ni < 4; ni++) {
      f32x4 z = {0.f, 0.f, 0.f, 0.f};
#pragma unroll
      for (int kc = 0; kc < 4; kc++) {
        short8 vf = *(const short8*)&PVT[ni * 16 + c16][kc * 32 + g * 8];
        z = __builtin_amdgcn_mfma_f32_16x16x32_bf16(wf[kc], vf, z, 0, 0, 0);
      }
      zz[ni] = z;
    }
    __builtin_amdgcn_s_setprio(0);
#pragma unroll
    for (int ni = 0; ni < 4; ni++) {
      float km = kwst[KWPER * 64 + ki * 64 + ni * 16 + c16];
#pragma unroll
      for (int rr = 0; rr < 4; rr++) accO[ni][rr] += zz[ni][rr] * km;
    }
    __syncthreads();
  }
  float* dst = partial + (size_t)chunk * M_ * H_;
#pragma unroll
  for (int ni = 0; ni < 4; ni++)
#pragma unroll
    for (int rr = 0; rr < 4; rr++) {
      int q = wid * 16 + g * 4 + rr;
      dst[(size_t)(b * 128 + q) * H_ + h * HD_ + ni * 16 + c16] = accO[ni][rr];
    }
}

__global__ void k_reduce(const float* __restrict__ partial, unsigned short* __restrict__ ctxsum) {
  int i = (blockIdx.x * 256 + threadIdx.x) * 4;
  float4 s = *(const float4*)&partial[i];
#pragma unroll
  for (int c = 1; c < NCHUNK; c++) {
    float4 v = *(const float4*)&partial[(size_t)c * M_ * H_ + i];
    s.x += v.x; s.y += v.y; s.z += v.z; s.w += v.w;
  }
  uint2 o;
  o.x = (unsigned)f2b(s.x) | ((unsigned)f2b(s.y) << 16);
  o.y = (unsigned)f2b(s.z) | ((unsigned)f2b(s.w) << 16);
  *(uint2*)&ctxsum[i] = o;
}

__launch_bounds__(256)
__global__ void k_ln(const float* __restrict__ x, const float* __restrict__ gamma,
                     const float* __restrict__ beta, float* __restrict__ out) {
  __shared__ float red[8];
  int row = blockIdx.x, t = threadIdx.x;
  int lane = t & 63, wid = t >> 6;
  const float* xr = x + (size_t)row * H_;
  float v[3];
#pragma unroll
  for (int j = 0; j < 3; j++) v[j] = xr[t + j * 256];
  float s = v[0] + v[1] + v[2];
#pragma unroll
  for (int off = 1; off < 64; off <<= 1) s += __shfl_xor(s, off);
  if (lane == 0) red[wid] = s;
  __syncthreads();
  float mu = (red[0] + red[1] + red[2] + red[3]) * (1.f / 768.f);
  float q = 0.f;
#pragma unroll
  for (int j = 0; j < 3; j++) { float d = v[j] - mu; q += d * d; }
#pragma unroll
  for (int off = 1; off < 64; off <<= 1) q += __shfl_xor(q, off);
  if (lane == 0) red[4 + wid] = q;
  __syncthreads();
  float var = (red[4] + red[5] + red[6] + red[7]) * (1.f / 768.f);
  float rstd = rsqrtf(var + 1e-12f);
#pragma unroll
  for (int j = 0; j < 3; j++) {
    int c = t + j * 256;
    out[(size_t)row * H_ + c] = gamma[c] * ((v[j] - mu) * rstd) + beta[c];
  }
}

// ---------------- launch ----------------

extern "C" void kernel_launch(void* const* d_in, const int* in_sizes, int n_in,
                              void* d_out, int out_size, void* d_ws, size_t ws_size,
                              hipStream_t stream) {
  const float* hidden = (const float*)d_in[0];
  const float* posk   = (const float*)d_in[1];
  const float* negk   = (const float*)d_in[2];
  const float* mask   = (const float*)d_in[3];
  const float* Wq     = (const float*)d_in[4];
  const float* Wk     = (const float*)d_in[5];
  const float* Wv     = (const float*)d_in[6];
  const float* Wo     = (const float*)d_in[7];
  const float* bo     = (const float*)d_in[8];
  const float* Wmlp   = (const float*)d_in[9];
  const float* bmlp   = (const float*)d_in[10];
  const float* Wdown  = (const float*)d_in[11];
  const float* bdown  = (const float*)d_in[12];
  const float* Wup    = (const float*)d_in[13];
  const float* bup    = (const float*)d_in[14];
  const float* gamma  = (const float*)d_in[15];
  const float* beta   = (const float*)d_in[16];

  char* ws = (char*)d_ws;
  size_t off = 0;
  auto alloc = [&](size_t bytes) -> void* {
    void* p = ws + off;
    off += (bytes + 255) & ~(size_t)255;
    return p;
  };
  unsigned short* hb     = (unsigned short*)alloc((size_t)M_ * H_ * 2);
  unsigned short* qkvT   = (unsigned short*)alloc((size_t)QKVN * H_ * 2);
  unsigned short* WoT    = (unsigned short*)alloc((size_t)H_ * H_ * 2);
  unsigned short* WdownT = (unsigned short*)alloc((size_t)I_ * H_ * 2);
  unsigned short* WupT   = (unsigned short*)alloc((size_t)H_ * I_ * 2);
  unsigned short* PQKV   = (unsigned short*)alloc((size_t)M_ * QKVN * 2);
  float* kw2s    = (float*)alloc((size_t)KW_ * H_ * 4);
  float* kwm     = (float*)alloc((size_t)KW_ * H_ * 4);
  float* c0      = (float*)alloc((size_t)H_ * 4);
  float* partial = (float*)alloc((size_t)NCHUNK * M_ * H_ * 4);
  unsigned short* ctxsum = (unsigned short*)alloc((size_t)M_ * H_ * 2);
  float* fusedF  = (float*)alloc((size_t)M_ * H_ * 4);
  unsigned short* fusedB = (unsigned short*)alloc((size_t)M_ * H_ * 2);
  unsigned short* downB  = (unsigned short*)alloc((size_t)M_ * I_ * 2);
  float* xF      = (float*)alloc((size_t)M_ * H_ * 4);

  k_f32_to_bf16<<<768, 256, 0, stream>>>(hidden, hb, M_ * H_);
  k_transpose_bf16<<<dim3(24, 24), 256, 0, stream>>>(Wq, qkvT, 768, 768);
  k_transpose_bf16<<<dim3(24, 24), 256, 0, stream>>>(Wk, qkvT + 768 * 768, 768, 768);
  k_transpose_bf16<<<dim3(24, 24), 256, 0, stream>>>(Wv, qkvT + 2 * 768 * 768, 768, 768);
  k_transpose_bf16<<<dim3(24, 24), 256, 0, stream>>>(Wo, WoT, 768, 768);
  k_transpose_bf16<<<dim3(96, 24), 256, 0, stream>>>(Wdown, WdownT, 768, 3072);
  k_transpose_bf16<<<dim3(24, 96), 256, 0, stream>>>(Wup, WupT, 3072, 768);
  k_prep_kw<<<300, 256, 0, stream>>>(posk, negk, Wmlp, kw2s, kwm);
  k_prep_c0<<<1, 256, 0, stream>>>(Wmlp, bmlp, bo, c0);

  k_gemm_bt<0><<<dim3(18, 8), 256, 0, stream>>>(hb, qkvT, M_, QKVN, H_, nullptr, PQKV, nullptr, nullptr);
  k_attn<<<dim3(NCHUNK, NH_, B_), 512, 0, stream>>>(PQKV, mask, kw2s, kwm, partial);
  k_reduce<<<768, 256, 0, stream>>>(partial, ctxsum);
  k_gemm_bt<1><<<dim3(6, 8), 256, 0, stream>>>(ctxsum, WoT, M_, H_, H_, fusedF, fusedB, c0, nullptr);
  k_gemm_bt<2><<<dim3(24, 8), 256, 0, stream>>>(fusedB, WdownT, M_, I_, H_, nullptr, downB, bdown, nullptr);
  k_gemm_bt<3><<<dim3(6, 8), 256, 0, stream>>>(downB, WupT, M_, H_, I_, xF, nullptr, bup, fusedF);
  k_ln<<<M_, 256, 0, stream>>>(xF, gamma, beta, (float*)d_out);
}

// Round 3
// 210.794 us; speedup vs baseline: 1.5768x; 1.3776x over previous
//
#include <hip/hip_runtime.h>
#include <hip/hip_bf16.h>
#include <math.h>

#define B_ 8
#define S_ 128
#define H_ 768
#define NH_ 12
#define HD_ 64
#define M_ 1024
#define KW_ 100
#define I_ 3072
#define QKVN 2304
#define NCHUNK 10
#define KWPER 10
#define LOG2E 1.4426950408889634f

typedef __attribute__((ext_vector_type(8))) short short8;
typedef __attribute__((ext_vector_type(8))) unsigned short ushort8;
typedef __attribute__((ext_vector_type(4))) float f32x4;

static __device__ __forceinline__ unsigned short f2b(float f) {
  union { float f; unsigned int u; } v; v.f = f;
  return (unsigned short)((v.u + 0x7fffu + ((v.u >> 16) & 1u)) >> 16);
}
static __device__ __forceinline__ float b2f(unsigned short b) {
  union { unsigned int u; float f; } v; v.u = ((unsigned int)b) << 16;
  return v.f;
}

// ---------------- merged prep kernel ----------------
// grid (96, 24, 7), 256 threads.
// z 0..3: transpose Wq/Wk/Wv/Wo (768x768, active bx<24)
// z 4: Wdown (768x3072) transpose ; z 5: Wup (3072x768) transpose
// z 6: linear blocks: [0,768) hidden f32->bf16 cast; [768,1068) kw prep; 1068 c0
__global__ void k_prep(const float* __restrict__ hidden,
                       const float* __restrict__ Wq, const float* __restrict__ Wk,
                       const float* __restrict__ Wv, const float* __restrict__ Wo,
                       const float* __restrict__ Wdown, const float* __restrict__ Wup,
                       const float* __restrict__ posk, const float* __restrict__ negk,
                       const float* __restrict__ Wmlp, const float* __restrict__ bmlp,
                       const float* __restrict__ bo,
                       unsigned short* __restrict__ hb, unsigned short* __restrict__ qkvT,
                       unsigned short* __restrict__ WoT, unsigned short* __restrict__ WdownT,
                       unsigned short* __restrict__ WupT,
                       float* __restrict__ kw2s, float* __restrict__ kwm, float* __restrict__ c0) {
  __shared__ float tile[32][33];
  int z = blockIdx.z;
  int t = threadIdx.x;
  if (z == 6) {
    int n = blockIdx.y * 96 + blockIdx.x;
    if (n < 768) {
      int i = (n * 256 + t) * 4;
      float4 v = *(const float4*)&hidden[i];
      uint2 o;
      o.x = (unsigned)f2b(v.x) | ((unsigned)f2b(v.y) << 16);
      o.y = (unsigned)f2b(v.z) | ((unsigned)f2b(v.w) << 16);
      *(uint2*)&hb[i] = o;
    } else if (n < 1068) {
      int idx = (n - 768) * 256 + t;
      if (idx < KW_ * H_) {
        int j = idx / H_, d = idx - j * H_;
        float v = (j & 1) ? negk[(j >> 1) * H_ + d] : posk[(j >> 1) * H_ + d];
        kw2s[idx] = v * v * 0.125f * LOG2E;
        kwm[idx] = v * Wmlp[j];
      }
    } else if (n == 1068) {
      __shared__ float red[256];
      red[t] = (t < KW_) ? Wmlp[t] : 0.f;
      __syncthreads();
      for (int s = 128; s > 0; s >>= 1) { if (t < s) red[t] += red[t + s]; __syncthreads(); }
      float sWm = red[0];
      for (int c = t; c < H_; c += 256) c0[c] = sWm * bo[c] + bmlp[0];
    }
    return;
  }
  const float* src; unsigned short* dst; int R, C, r0, c0t;
  if (z < 4) {
    if (blockIdx.x >= 24) return;
    const float* srcs[4] = {Wq, Wk, Wv, Wo};
    src = srcs[z];
    dst = (z < 3) ? qkvT + (size_t)z * 768 * 768 : WoT;
    R = 768; C = 768; c0t = blockIdx.x * 32; r0 = blockIdx.y * 32;
  } else if (z == 4) {
    src = Wdown; dst = WdownT; R = 768; C = 3072;
    c0t = blockIdx.x * 32; r0 = blockIdx.y * 32;
  } else {
    src = Wup; dst = WupT; R = 3072; C = 768;
    c0t = blockIdx.y * 32; r0 = blockIdx.x * 32;
  }
  int tx = t & 31, ty = t >> 5;
#pragma unroll
  for (int i = 0; i < 4; i++)
    tile[ty + i * 8][tx] = src[(size_t)(r0 + ty + i * 8) * C + c0t + tx];
  __syncthreads();
#pragma unroll
  for (int i = 0; i < 4; i++)
    dst[(size_t)(c0t + ty + i * 8) * R + r0 + tx] = f2b(tile[tx][ty + i * 8]);
}

// ---------------- bf16 MFMA GEMM (fused epilogue, EPI2=gelu) ----------------
template <int EPI>
__launch_bounds__(256)
__global__ void k_gemm_bt(const unsigned short* __restrict__ A, const unsigned short* __restrict__ BT,
                          int M, int N, int K,
                          float* __restrict__ outF, unsigned short* __restrict__ outB,
                          const float* __restrict__ bias, const float* __restrict__ res) {
  __shared__ unsigned short Asm[128][56];
  __shared__ unsigned short Bsm[128][56];
  int tid = threadIdx.x;
  int lane = tid & 63, wid = tid >> 6;
  int g = lane >> 4, c16 = lane & 15;
  int wr = wid >> 1, wc = wid & 1;
  int m0 = blockIdx.y * 128, n0 = blockIdx.x * 128;
  f32x4 acc[4][4] = {};
  int r = tid >> 1, half = (tid & 1) * 16;
  const unsigned short* Ap = A + (size_t)(m0 + r) * K + half;
  const unsigned short* Bp = BT + (size_t)(n0 + r) * K + half;
  for (int kt = 0; kt < K; kt += 32) {
    __syncthreads();
    ushort8 a0 = *(const ushort8*)(Ap + kt);
    ushort8 a1 = *(const ushort8*)(Ap + kt + 8);
    ushort8 b0 = *(const ushort8*)(Bp + kt);
    ushort8 b1 = *(const ushort8*)(Bp + kt + 8);
    *(ushort8*)&Asm[r][half] = a0;  *(ushort8*)&Asm[r][half + 8] = a1;
    *(ushort8*)&Bsm[r][half] = b0;  *(ushort8*)&Bsm[r][half + 8] = b1;
    __syncthreads();
    short8 af[4], bf[4];
#pragma unroll
    for (int mi = 0; mi < 4; mi++) af[mi] = *(const short8*)&Asm[wr * 64 + mi * 16 + c16][g * 8];
#pragma unroll
    for (int ni = 0; ni < 4; ni++) bf[ni] = *(const short8*)&Bsm[wc * 64 + ni * 16 + c16][g * 8];
#pragma unroll
    for (int mi = 0; mi < 4; mi++)
#pragma unroll
      for (int ni = 0; ni < 4; ni++)
        acc[mi][ni] = __builtin_amdgcn_mfma_f32_16x16x32_bf16(af[mi], bf[ni], acc[mi][ni], 0, 0, 0);
  }
#pragma unroll
  for (int mi = 0; mi < 4; mi++)
#pragma unroll
    for (int ni = 0; ni < 4; ni++)
#pragma unroll
      for (int rr = 0; rr < 4; rr++) {
        int row = m0 + wr * 64 + mi * 16 + g * 4 + rr;
        int col = n0 + wc * 64 + ni * 16 + c16;
        float v = acc[mi][ni][rr];
        if (EPI == 0) {
          outB[(size_t)row * N + col] = f2b(v);
        } else if (EPI == 2) {
          float t = v + bias[col];
          float gl = 0.5f * t * (1.f + erff(t * 0.70710678118f));
          outB[(size_t)row * N + col] = f2b(gl);
        }
      }
}

// ---------------- split-K GEMM -> f32 partials ----------------
__launch_bounds__(256)
__global__ void k_gemm_sk(const unsigned short* __restrict__ A, const unsigned short* __restrict__ BT,
                          int M, int N, int K, int ksl, float* __restrict__ pOut) {
  __shared__ unsigned short Asm[128][56];
  __shared__ unsigned short Bsm[128][56];
  int tid = threadIdx.x;
  int lane = tid & 63, wid = tid >> 6;
  int g = lane >> 4, c16 = lane & 15;
  int wr = wid >> 1, wc = wid & 1;
  int m0 = blockIdx.y * 128, n0 = blockIdx.x * 128;
  int kstart = blockIdx.z * ksl;
  f32x4 acc[4][4] = {};
  int r = tid >> 1, half = (tid & 1) * 16;
  const unsigned short* Ap = A + (size_t)(m0 + r) * K + half + kstart;
  const unsigned short* Bp = BT + (size_t)(n0 + r) * K + half + kstart;
  for (int kt = 0; kt < ksl; kt += 32) {
    __syncthreads();
    ushort8 a0 = *(const ushort8*)(Ap + kt);
    ushort8 a1 = *(const ushort8*)(Ap + kt + 8);
    ushort8 b0 = *(const ushort8*)(Bp + kt);
    ushort8 b1 = *(const ushort8*)(Bp + kt + 8);
    *(ushort8*)&Asm[r][half] = a0;  *(ushort8*)&Asm[r][half + 8] = a1;
    *(ushort8*)&Bsm[r][half] = b0;  *(ushort8*)&Bsm[r][half + 8] = b1;
    __syncthreads();
    short8 af[4], bf[4];
#pragma unroll
    for (int mi = 0; mi < 4; mi++) af[mi] = *(const short8*)&Asm[wr * 64 + mi * 16 + c16][g * 8];
#pragma unroll
    for (int ni = 0; ni < 4; ni++) bf[ni] = *(const short8*)&Bsm[wc * 64 + ni * 16 + c16][g * 8];
#pragma unroll
    for (int mi = 0; mi < 4; mi++)
#pragma unroll
      for (int ni = 0; ni < 4; ni++)
        acc[mi][ni] = __builtin_amdgcn_mfma_f32_16x16x32_bf16(af[mi], bf[ni], acc[mi][ni], 0, 0, 0);
  }
  float* dst = pOut + (size_t)blockIdx.z * M * N;
#pragma unroll
  for (int mi = 0; mi < 4; mi++)
#pragma unroll
    for (int ni = 0; ni < 4; ni++)
#pragma unroll
      for (int rr = 0; rr < 4; rr++) {
        int row = m0 + wr * 64 + mi * 16 + g * 4 + rr;
        int col = n0 + wc * 64 + ni * 16 + c16;
        dst[(size_t)row * N + col] = acc[mi][ni][rr];
      }
}

// reduce SPLITS partials (+ optional bias epilogue)
template <int SPLITS, int EPI>
__global__ void k_red(const float* __restrict__ p, const float* __restrict__ bias,
                      float* __restrict__ outF, unsigned short* __restrict__ outB, int N) {
  int i = (blockIdx.x * 256 + threadIdx.x) * 4;
  const size_t MN = (size_t)M_ * N;
  float4 s = *(const float4*)&p[i];
#pragma unroll
  for (int c = 1; c < SPLITS; c++) {
    float4 v = *(const float4*)&p[c * MN + i];
    s.x += v.x; s.y += v.y; s.z += v.z; s.w += v.w;
  }
  if (EPI == 1) {
    int col = i % N;
    s.x += bias[col]; s.y += bias[col + 1]; s.z += bias[col + 2]; s.w += bias[col + 3];
    *(float4*)&outF[i] = s;
  }
  uint2 o;
  o.x = (unsigned)f2b(s.x) | ((unsigned)f2b(s.y) << 16);
  o.y = (unsigned)f2b(s.z) | ((unsigned)f2b(s.w) << 16);
  *(uint2*)&outB[i] = o;
}

// ---------------- fused keyword attention (v3) ----------------
// grid (NCHUNK, NH_, B_), 512 threads, 3 blocks/CU (54KB LDS).
// No mask (cancels in column-softmax), no max-subtraction (scores bounded),
// K-fragment from global per kw (wave-private 2x16B), WL writes packed b32.

static __device__ __forceinline__ int swzA(int r, int c) {
  return (((r << 7) + (c << 1)) ^ ((r & 7) << 4)) >> 1;
}
static __device__ __forceinline__ int swzW(int r, int c) {
  return (((r << 8) + (c << 1)) ^ (((r >> 1) & 7) << 4)) >> 1;
}

__launch_bounds__(512, 8)
__global__ void k_attn(const unsigned short* __restrict__ PQKV,
                       const float* __restrict__ kw2s, const float* __restrict__ kwm,
                       float* __restrict__ partial) {
  __shared__ unsigned short WLAS[128 * 128];   // 32KB: AS (first 16KB, swzA) / WL (swzW)
  __shared__ unsigned short PVT[64][136];      // 17408B, padded
  __shared__ float kw2L[KWPER * 64];           // 2560B
  __shared__ unsigned short kwmL[KWPER * 64];  // 1280B
  int tid = threadIdx.x;
  int lane = tid & 63, wid = tid >> 6;
  int g = lane >> 4, c16 = lane & 15;
  int chunk = blockIdx.x, h = blockIdx.y, b = blockIdx.z;
  const size_t rowbase = (size_t)b * 128 * QKVN;
  int kq = tid >> 2, quarter = tid & 3;
  int kcol = wid * 16 + c16;
  // ---- prologue ----
  ushort8 q0, q1;
  {
    const unsigned short* srcv = PQKV + rowbase + (size_t)kq * QKVN + 2 * H_ + h * HD_ + quarter * 16;
    ushort8 w0 = *(const ushort8*)srcv;
    ushort8 w1 = *(const ushort8*)(srcv + 8);
#pragma unroll
    for (int j = 0; j < 8; j++) PVT[quarter * 16 + j][kq] = w0[j];
#pragma unroll
    for (int j = 0; j < 8; j++) PVT[quarter * 16 + 8 + j][kq] = w1[j];
    const unsigned short* srcq = PQKV + rowbase + (size_t)kq * QKVN + h * HD_ + quarter * 16;
    q0 = *(const ushort8*)srcq;
    q1 = *(const ushort8*)(srcq + 8);
    for (int i = tid; i < KWPER * 64; i += 512) {
      int ki = i >> 6, d = i & 63;
      size_t gi = (size_t)(chunk * KWPER + ki) * H_ + h * HD_ + d;
      kw2L[i] = kw2s[gi];
      kwmL[i] = f2b(kwm[gi]);
    }
  }
  const unsigned short* bkp = PQKV + rowbase + (size_t)kcol * QKVN + H_ + h * HD_;
  __syncthreads();
  float accO[4][4] = {};
  for (int ki = 0; ki < KWPER; ki++) {
    // K fragment (loop-invariant; compiler arbitrates reg vs reload under LB(512,8))
    ushort8 bk0 = *(const ushort8*)(bkp + g * 8);
    ushort8 bk1 = *(const ushort8*)(bkp + 32 + g * 8);
    // ---- AS[q][d] = bf16( PQ[q,d] * kw^2 * scale * log2e ), swzA ----
    {
      const float* kp = &kw2L[ki * 64 + quarter * 16];
      unsigned int o[8];
#pragma unroll
      for (int p = 0; p < 4; p++) {
        float2 cc = *(const float2*)&kp[2 * p];
        float lo = b2f(q0[2 * p]) * cc.x;
        float hi = b2f(q0[2 * p + 1]) * cc.y;
        asm("v_cvt_pk_bf16_f32 %0, %1, %2" : "=v"(o[p]) : "v"(lo), "v"(hi));
      }
#pragma unroll
      for (int p = 0; p < 4; p++) {
        float2 cc = *(const float2*)&kp[8 + 2 * p];
        float lo = b2f(q1[2 * p]) * cc.x;
        float hi = b2f(q1[2 * p + 1]) * cc.y;
        asm("v_cvt_pk_bf16_f32 %0, %1, %2" : "=v"(o[4 + p]) : "v"(lo), "v"(hi));
      }
      *(uint4*)&WLAS[swzA(kq, quarter * 16)] = *(const uint4*)&o[0];
      *(uint4*)&WLAS[swzA(kq, quarter * 16 + 8)] = *(const uint4*)&o[4];
    }
    __syncthreads();
    // ---- QK^T ----
    f32x4 sc[8];
    __builtin_amdgcn_s_setprio(1);
#pragma unroll
    for (int mi = 0; mi < 8; mi++) {
      short8 aq0 = *(const short8*)&WLAS[swzA(mi * 16 + c16, g * 8)];
      short8 aq1 = *(const short8*)&WLAS[swzA(mi * 16 + c16, 32 + g * 8)];
      f32x4 z = {0.f, 0.f, 0.f, 0.f};
      z = __builtin_amdgcn_mfma_f32_16x16x32_bf16(aq0, *(const short8*)&bk0, z, 0, 0, 0);
      z = __builtin_amdgcn_mfma_f32_16x16x32_bf16(aq1, *(const short8*)&bk1, z, 0, 0, 0);
      sc[mi] = z;
    }
    __builtin_amdgcn_s_setprio(0);
    // ---- column softmax over q: exp2 direct (no max-sub; scores bounded) ----
    float sm = 0.f;
#pragma unroll
    for (int mi = 0; mi < 8; mi++)
#pragma unroll
      for (int rr = 0; rr < 4; rr++) { float e = __builtin_amdgcn_exp2f(sc[mi][rr]); sc[mi][rr] = e; sm += e; }
    sm += __shfl_xor(sm, 16);
    sm += __shfl_xor(sm, 32);
    float rinv = 1.0f / sm;
    __syncthreads();  // AS reads complete before WL overwrite
    // ---- WL[q][k] packed b32 writes (lane^1 pairing), swzW ----
    unsigned baseoff = ((unsigned)(g * 4) << 8) + ((unsigned)(kcol & ~1) << 1);
    baseoff ^= (unsigned)(g * 32);
#pragma unroll
    for (int mi = 0; mi < 8; mi++) {
      float a0 = sc[mi][0] * rinv, a1 = sc[mi][1] * rinv;
      float a2 = sc[mi][2] * rinv, a3 = sc[mi][3] * rinv;
      unsigned pk0, pk1;
      asm("v_cvt_pk_bf16_f32 %0, %1, %2" : "=v"(pk0) : "v"(a0), "v"(a1));
      asm("v_cvt_pk_bf16_f32 %0, %1, %2" : "=v"(pk1) : "v"(a2), "v"(a3));
      unsigned px0 = __shfl_xor(pk0, 1);
      unsigned px1 = __shfl_xor(pk1, 1);
      if (!(lane & 1)) {
        unsigned w0 = (pk0 & 0xffffu) | (px0 << 16);
        unsigned w1 = (pk0 >> 16) | (px0 & 0xffff0000u);
        unsigned w2 = (pk1 & 0xffffu) | (px1 << 16);
        unsigned w3 = (pk1 >> 16) | (px1 & 0xffff0000u);
        unsigned off1 = baseoff + (unsigned)mi * 4096u;
        unsigned off2 = (off1 + 512u) ^ 16u;
        *(unsigned*)((char*)WLAS + off1) = w0;
        *(unsigned*)((char*)WLAS + off1 + 256) = w1;
        *(unsigned*)((char*)WLAS + off2) = w2;
        *(unsigned*)((char*)WLAS + off2 + 256) = w3;
      }
    }
    __syncthreads();
    // ---- PV ----
    short8 wf[4];
#pragma unroll
    for (int kc = 0; kc < 4; kc++) wf[kc] = *(const short8*)&WLAS[swzW(wid * 16 + c16, kc * 32 + g * 8)];
    __builtin_amdgcn_s_setprio(1);
    f32x4 zz[4];
#pragma unroll
    for (int ni = 0; ni < 4; ni++) {
      f32x4 z = {0.f, 0.f, 0.f, 0.f};
#pragma unroll
      for (int kc = 0; kc < 4; kc++) {
        short8 vf = *(const short8*)&PVT[ni * 16 + c16][kc * 32 + g * 8];
        z = __builtin_amdgcn_mfma_f32_16x16x32_bf16(wf[kc], vf, z, 0, 0, 0);
      }
      zz[ni] = z;
    }
    __builtin_amdgcn_s_setprio(0);
#pragma unroll
    for (int ni = 0; ni < 4; ni++) {
      float km = b2f(kwmL[ki * 64 + ni * 16 + c16]);
#pragma unroll
      for (int rr = 0; rr < 4; rr++) accO[ni][rr] += zz[ni][rr] * km;
    }
    __syncthreads();
  }
  float* dst = partial + (size_t)chunk * M_ * H_;
#pragma unroll
  for (int ni = 0; ni < 4; ni++)
#pragma unroll
    for (int rr = 0; rr < 4; rr++) {
      int q = wid * 16 + g * 4 + rr;
      dst[(size_t)(b * 128 + q) * H_ + h * HD_ + ni * 16 + c16] = accO[ni][rr];
    }
}

__global__ void k_reduce(const float* __restrict__ partial, unsigned short* __restrict__ ctxsum) {
  int i = (blockIdx.x * 256 + threadIdx.x) * 4;
  float4 s = *(const float4*)&partial[i];
#pragma unroll
  for (int c = 1; c < NCHUNK; c++) {
    float4 v = *(const float4*)&partial[(size_t)c * M_ * H_ + i];
    s.x += v.x; s.y += v.y; s.z += v.z; s.w += v.w;
  }
  uint2 o;
  o.x = (unsigned)f2b(s.x) | ((unsigned)f2b(s.y) << 16);
  o.y = (unsigned)f2b(s.z) | ((unsigned)f2b(s.w) << 16);
  *(uint2*)&ctxsum[i] = o;
}

// LayerNorm with fused up-proj split-K reduce + bias + residual
__launch_bounds__(256)
__global__ void k_ln2(const float* __restrict__ pUp, const float* __restrict__ bup,
                      const float* __restrict__ fusedF,
                      const float* __restrict__ gamma, const float* __restrict__ beta,
                      float* __restrict__ out) {
  __shared__ float red[8];
  int row = blockIdx.x, t = threadIdx.x;
  int lane = t & 63, wid = t >> 6;
  const size_t MN = (size_t)M_ * H_;
  const size_t rb = (size_t)row * H_;
  float v[3];
#pragma unroll
  for (int j = 0; j < 3; j++) {
    int c = t + j * 256;
    float x = pUp[rb + c] + pUp[MN + rb + c] + pUp[2 * MN + rb + c] + pUp[3 * MN + rb + c];
    v[j] = x + bup[c] + fusedF[rb + c];
  }
  float s = v[0] + v[1] + v[2];
#pragma unroll
  for (int off = 1; off < 64; off <<= 1) s += __shfl_xor(s, off);
  if (lane == 0) red[wid] = s;
  __syncthreads();
  float mu = (red[0] + red[1] + red[2] + red[3]) * (1.f / 768.f);
  float q = 0.f;
#pragma unroll
  for (int j = 0; j < 3; j++) { float d = v[j] - mu; q += d * d; }
#pragma unroll
  for (int off = 1; off < 64; off <<= 1) q += __shfl_xor(q, off);
  if (lane == 0) red[4 + wid] = q;
  __syncthreads();
  float var = (red[4] + red[5] + red[6] + red[7]) * (1.f / 768.f);
  float rstd = rsqrtf(var + 1e-12f);
#pragma unroll
  for (int j = 0; j < 3; j++) {
    int c = t + j * 256;
    out[rb + c] = gamma[c] * ((v[j] - mu) * rstd) + beta[c];
  }
}

// ---------------- launch ----------------

extern "C" void kernel_launch(void* const* d_in, const int* in_sizes, int n_in,
                              void* d_out, int out_size, void* d_ws, size_t ws_size,
                              hipStream_t stream) {
  const float* hidden = (const float*)d_in[0];
  const float* posk   = (const float*)d_in[1];
  const float* negk   = (const float*)d_in[2];
  const float* Wq     = (const float*)d_in[4];
  const float* Wk     = (const float*)d_in[5];
  const float* Wv     = (const float*)d_in[6];
  const float* Wo     = (const float*)d_in[7];
  const float* bo     = (const float*)d_in[8];
  const float* Wmlp   = (const float*)d_in[9];
  const float* bmlp   = (const float*)d_in[10];
  const float* Wdown  = (const float*)d_in[11];
  const float* bdown  = (const float*)d_in[12];
  const float* Wup    = (const float*)d_in[13];
  const float* bup    = (const float*)d_in[14];
  const float* gamma  = (const float*)d_in[15];
  const float* beta   = (const float*)d_in[16];

  char* ws = (char*)d_ws;
  size_t off = 0;
  auto alloc = [&](size_t bytes) -> void* {
    void* p = ws + off;
    off += (bytes + 255) & ~(size_t)255;
    return p;
  };
  unsigned short* hb     = (unsigned short*)alloc((size_t)M_ * H_ * 2);
  unsigned short* qkvT   = (unsigned short*)alloc((size_t)QKVN * H_ * 2);
  unsigned short* WoT    = (unsigned short*)alloc((size_t)H_ * H_ * 2);
  unsigned short* WdownT = (unsigned short*)alloc((size_t)I_ * H_ * 2);
  unsigned short* WupT   = (unsigned short*)alloc((size_t)H_ * I_ * 2);
  unsigned short* PQKV   = (unsigned short*)alloc((size_t)M_ * QKVN * 2);
  float* kw2s    = (float*)alloc((size_t)KW_ * H_ * 4);
  float* kwm     = (float*)alloc((size_t)KW_ * H_ * 4);
  float* c0      = (float*)alloc((size_t)H_ * 4);
  float* partial = (float*)alloc((size_t)NCHUNK * M_ * H_ * 4);  // 30MB, aliased by GEMM split-K partials
  unsigned short* ctxsum = (unsigned short*)alloc((size_t)M_ * H_ * 2);
  float* fusedF  = (float*)alloc((size_t)M_ * H_ * 4);
  unsigned short* fusedB = (unsigned short*)alloc((size_t)M_ * H_ * 2);
  unsigned short* downB  = (unsigned short*)alloc((size_t)M_ * I_ * 2);

  k_prep<<<dim3(96, 24, 7), 256, 0, stream>>>(hidden, Wq, Wk, Wv, Wo, Wdown, Wup,
                                              posk, negk, Wmlp, bmlp, bo,
                                              hb, qkvT, WoT, WdownT, WupT, kw2s, kwm, c0);
  // QKV projection: split-K x2 -> f32 partial -> bf16 PQKV
  k_gemm_sk<<<dim3(18, 8, 2), 256, 0, stream>>>(hb, qkvT, M_, QKVN, H_, 384, partial);
  k_red<2, 0><<<2304, 256, 0, stream>>>(partial, nullptr, nullptr, PQKV, QKVN);
  k_attn<<<dim3(NCHUNK, NH_, B_), 512, 0, stream>>>(PQKV, kw2s, kwm, partial);
  k_reduce<<<768, 256, 0, stream>>>(partial, ctxsum);
  // Wo: split-K x2 ; reduce adds c0 (= sum(Wmlp)*bo + bmlp)
  k_gemm_sk<<<dim3(6, 8, 2), 256, 0, stream>>>(ctxsum, WoT, M_, H_, H_, 384, partial);
  k_red<2, 1><<<768, 256, 0, stream>>>(partial, c0, fusedF, fusedB, H_);
  // down-proj: fused gelu epilogue (192 blocks, no split needed)
  k_gemm_bt<2><<<dim3(24, 8), 256, 0, stream>>>(fusedB, WdownT, M_, I_, H_, nullptr, downB, bdown, nullptr);
  // up-proj: split-K x4 ; reduce + bias + residual + LN fused into k_ln2
  k_gemm_sk<<<dim3(6, 8, 4), 256, 0, stream>>>(downB, WupT, M_, H_, I_, 768, partial);
  k_ln2<<<M_, 256, 0, stream>>>(partial, bup, fusedF, gamma, beta, (float*)d_out);
}

// Round 4
// 207.603 us; speedup vs baseline: 1.6011x; 1.0154x over previous
//
#include <hip/hip_runtime.h>
#include <hip/hip_bf16.h>
#include <math.h>

#define B_ 8
#define S_ 128
#define H_ 768
#define NH_ 12
#define HD_ 64
#define M_ 1024
#define KW_ 100
#define I_ 3072
#define QKVN 2304
#define NCHUNK 10
#define KWPER 10
#define LOG2E 1.4426950408889634f

typedef __attribute__((ext_vector_type(8))) short short8;
typedef __attribute__((ext_vector_type(8))) unsigned short ushort8;
typedef __attribute__((ext_vector_type(4))) float f32x4;

static __device__ __forceinline__ unsigned short f2b(float f) {
  union { float f; unsigned int u; } v; v.f = f;
  return (unsigned short)((v.u + 0x7fffu + ((v.u >> 16) & 1u)) >> 16);
}
static __device__ __forceinline__ float b2f(unsigned short b) {
  union { unsigned int u; float f; } v; v.u = ((unsigned int)b) << 16;
  return v.f;
}

// ---------------- merged prep kernel ----------------
__global__ void k_prep(const float* __restrict__ hidden,
                       const float* __restrict__ Wq, const float* __restrict__ Wk,
                       const float* __restrict__ Wv, const float* __restrict__ Wo,
                       const float* __restrict__ Wdown, const float* __restrict__ Wup,
                       const float* __restrict__ posk, const float* __restrict__ negk,
                       const float* __restrict__ Wmlp, const float* __restrict__ bmlp,
                       const float* __restrict__ bo,
                       unsigned short* __restrict__ hb, unsigned short* __restrict__ qkvT,
                       unsigned short* __restrict__ WoT, unsigned short* __restrict__ WdownT,
                       unsigned short* __restrict__ WupT,
                       float* __restrict__ kw2s, float* __restrict__ kwm, float* __restrict__ c0) {
  __shared__ float tile[32][33];
  int z = blockIdx.z;
  int t = threadIdx.x;
  if (z == 6) {
    int n = blockIdx.y * 96 + blockIdx.x;
    if (n < 768) {
      int i = (n * 256 + t) * 4;
      float4 v = *(const float4*)&hidden[i];
      uint2 o;
      o.x = (unsigned)f2b(v.x) | ((unsigned)f2b(v.y) << 16);
      o.y = (unsigned)f2b(v.z) | ((unsigned)f2b(v.w) << 16);
      *(uint2*)&hb[i] = o;
    } else if (n < 1068) {
      int idx = (n - 768) * 256 + t;
      if (idx < KW_ * H_) {
        int j = idx / H_, d = idx - j * H_;
        float v = (j & 1) ? negk[(j >> 1) * H_ + d] : posk[(j >> 1) * H_ + d];
        kw2s[idx] = v * v * 0.125f * LOG2E;
        kwm[idx] = v * Wmlp[j];
      }
    } else if (n == 1068) {
      __shared__ float red[256];
      red[t] = (t < KW_) ? Wmlp[t] : 0.f;
      __syncthreads();
      for (int s = 128; s > 0; s >>= 1) { if (t < s) red[t] += red[t + s]; __syncthreads(); }
      float sWm = red[0];
      for (int c = t; c < H_; c += 256) c0[c] = sWm * bo[c] + bmlp[0];
    }
    return;
  }
  const float* src; unsigned short* dst; int R, C, r0, c0t;
  if (z < 4) {
    if (blockIdx.x >= 24) return;
    const float* srcs[4] = {Wq, Wk, Wv, Wo};
    src = srcs[z];
    dst = (z < 3) ? qkvT + (size_t)z * 768 * 768 : WoT;
    R = 768; C = 768; c0t = blockIdx.x * 32; r0 = blockIdx.y * 32;
  } else if (z == 4) {
    src = Wdown; dst = WdownT; R = 768; C = 3072;
    c0t = blockIdx.x * 32; r0 = blockIdx.y * 32;
  } else {
    src = Wup; dst = WupT; R = 3072; C = 768;
    c0t = blockIdx.y * 32; r0 = blockIdx.x * 32;
  }
  int tx = t & 31, ty = t >> 5;
#pragma unroll
  for (int i = 0; i < 4; i++)
    tile[ty + i * 8][tx] = src[(size_t)(r0 + ty + i * 8) * C + c0t + tx];
  __syncthreads();
#pragma unroll
  for (int i = 0; i < 4; i++)
    dst[(size_t)(c0t + ty + i * 8) * R + r0 + tx] = f2b(tile[tx][ty + i * 8]);
}

// ---------------- bf16 MFMA GEMM (fused epilogue, EPI2=gelu) ----------------
template <int EPI>
__launch_bounds__(256)
__global__ void k_gemm_bt(const unsigned short* __restrict__ A, const unsigned short* __restrict__ BT,
                          int M, int N, int K,
                          float* __restrict__ outF, unsigned short* __restrict__ outB,
                          const float* __restrict__ bias, const float* __restrict__ res) {
  __shared__ unsigned short Asm[128][56];
  __shared__ unsigned short Bsm[128][56];
  int tid = threadIdx.x;
  int lane = tid & 63, wid = tid >> 6;
  int g = lane >> 4, c16 = lane & 15;
  int wr = wid >> 1, wc = wid & 1;
  int m0 = blockIdx.y * 128, n0 = blockIdx.x * 128;
  f32x4 acc[4][4] = {};
  int r = tid >> 1, half = (tid & 1) * 16;
  const unsigned short* Ap = A + (size_t)(m0 + r) * K + half;
  const unsigned short* Bp = BT + (size_t)(n0 + r) * K + half;
  for (int kt = 0; kt < K; kt += 32) {
    __syncthreads();
    ushort8 a0 = *(const ushort8*)(Ap + kt);
    ushort8 a1 = *(const ushort8*)(Ap + kt + 8);
    ushort8 b0 = *(const ushort8*)(Bp + kt);
    ushort8 b1 = *(const ushort8*)(Bp + kt + 8);
    *(ushort8*)&Asm[r][half] = a0;  *(ushort8*)&Asm[r][half + 8] = a1;
    *(ushort8*)&Bsm[r][half] = b0;  *(ushort8*)&Bsm[r][half + 8] = b1;
    __syncthreads();
    short8 af[4], bf[4];
#pragma unroll
    for (int mi = 0; mi < 4; mi++) af[mi] = *(const short8*)&Asm[wr * 64 + mi * 16 + c16][g * 8];
#pragma unroll
    for (int ni = 0; ni < 4; ni++) bf[ni] = *(const short8*)&Bsm[wc * 64 + ni * 16 + c16][g * 8];
#pragma unroll
    for (int mi = 0; mi < 4; mi++)
#pragma unroll
      for (int ni = 0; ni < 4; ni++)
        acc[mi][ni] = __builtin_amdgcn_mfma_f32_16x16x32_bf16(af[mi], bf[ni], acc[mi][ni], 0, 0, 0);
  }
#pragma unroll
  for (int mi = 0; mi < 4; mi++)
#pragma unroll
    for (int ni = 0; ni < 4; ni++)
#pragma unroll
      for (int rr = 0; rr < 4; rr++) {
        int row = m0 + wr * 64 + mi * 16 + g * 4 + rr;
        int col = n0 + wc * 64 + ni * 16 + c16;
        float v = acc[mi][ni][rr];
        if (EPI == 0) {
          outB[(size_t)row * N + col] = f2b(v);
        } else if (EPI == 2) {
          float t = v + bias[col];
          float gl = 0.5f * t * (1.f + erff(t * 0.70710678118f));
          outB[(size_t)row * N + col] = f2b(gl);
        }
      }
}

// ---------------- split-K GEMM -> f32 partials ----------------
__launch_bounds__(256)
__global__ void k_gemm_sk(const unsigned short* __restrict__ A, const unsigned short* __restrict__ BT,
                          int M, int N, int K, int ksl, float* __restrict__ pOut) {
  __shared__ unsigned short Asm[128][56];
  __shared__ unsigned short Bsm[128][56];
  int tid = threadIdx.x;
  int lane = tid & 63, wid = tid >> 6;
  int g = lane >> 4, c16 = lane & 15;
  int wr = wid >> 1, wc = wid & 1;
  int m0 = blockIdx.y * 128, n0 = blockIdx.x * 128;
  int kstart = blockIdx.z * ksl;
  f32x4 acc[4][4] = {};
  int r = tid >> 1, half = (tid & 1) * 16;
  const unsigned short* Ap = A + (size_t)(m0 + r) * K + half + kstart;
  const unsigned short* Bp = BT + (size_t)(n0 + r) * K + half + kstart;
  for (int kt = 0; kt < ksl; kt += 32) {
    __syncthreads();
    ushort8 a0 = *(const ushort8*)(Ap + kt);
    ushort8 a1 = *(const ushort8*)(Ap + kt + 8);
    ushort8 b0 = *(const ushort8*)(Bp + kt);
    ushort8 b1 = *(const ushort8*)(Bp + kt + 8);
    *(ushort8*)&Asm[r][half] = a0;  *(ushort8*)&Asm[r][half + 8] = a1;
    *(ushort8*)&Bsm[r][half] = b0;  *(ushort8*)&Bsm[r][half + 8] = b1;
    __syncthreads();
    short8 af[4], bf[4];
#pragma unroll
    for (int mi = 0; mi < 4; mi++) af[mi] = *(const short8*)&Asm[wr * 64 + mi * 16 + c16][g * 8];
#pragma unroll
    for (int ni = 0; ni < 4; ni++) bf[ni] = *(const short8*)&Bsm[wc * 64 + ni * 16 + c16][g * 8];
#pragma unroll
    for (int mi = 0; mi < 4; mi++)
#pragma unroll
      for (int ni = 0; ni < 4; ni++)
        acc[mi][ni] = __builtin_amdgcn_mfma_f32_16x16x32_bf16(af[mi], bf[ni], acc[mi][ni], 0, 0, 0);
  }
  float* dst = pOut + (size_t)blockIdx.z * M * N;
#pragma unroll
  for (int mi = 0; mi < 4; mi++)
#pragma unroll
    for (int ni = 0; ni < 4; ni++)
#pragma unroll
      for (int rr = 0; rr < 4; rr++) {
        int row = m0 + wr * 64 + mi * 16 + g * 4 + rr;
        int col = n0 + wc * 64 + ni * 16 + c16;
        dst[(size_t)row * N + col] = acc[mi][ni][rr];
      }
}

// reduce SPLITS partials (+ optional bias epilogue)
template <int SPLITS, int EPI>
__global__ void k_red(const float* __restrict__ p, const float* __restrict__ bias,
                      float* __restrict__ outF, unsigned short* __restrict__ outB, int N) {
  int i = (blockIdx.x * 256 + threadIdx.x) * 4;
  const size_t MN = (size_t)M_ * N;
  float4 s = *(const float4*)&p[i];
#pragma unroll
  for (int c = 1; c < SPLITS; c++) {
    float4 v = *(const float4*)&p[c * MN + i];
    s.x += v.x; s.y += v.y; s.z += v.z; s.w += v.w;
  }
  if (EPI == 1) {
    int col = i % N;
    s.x += bias[col]; s.y += bias[col + 1]; s.z += bias[col + 2]; s.w += bias[col + 3];
    *(float4*)&outF[i] = s;
  }
  uint2 o;
  o.x = (unsigned)f2b(s.x) | ((unsigned)f2b(s.y) << 16);
  o.y = (unsigned)f2b(s.z) | ((unsigned)f2b(s.w) << 16);
  *(uint2*)&outB[i] = o;
}

// ---------------- fused keyword attention (v4: q-strip waves) ----------------
// grid (NCHUNK, NH_, B_), 512 threads (8 waves), 1 block/CU (VGPR-bound).
// Wave wid owns q-strip [wid*16, wid*16+16). K-frags (64 VGPR) and V-frags
// (64 VGPR) are loop-invariant registers; scaled-Q A-frag built in registers.
// Per kw: QK (16 MFMA) -> exp2 -> colsum (in-lane + 2 shfl + cross-wave LDS,
// 2 barriers) -> normalize -> per-wave WL round-trip (32 b16 w + 4 b128 r,
// XOR swizzled) -> PV (16 MFMA) -> kwm-scaled accumulate.

static __device__ __forceinline__ int swzA(int r, int c) {
  return (((r << 7) + (c << 1)) ^ ((r & 7) << 4)) >> 1;
}

__launch_bounds__(512, 2)
__global__ void k_attn(const unsigned short* __restrict__ PQKV,
                       const float* __restrict__ kw2s, const float* __restrict__ kwm,
                       float* __restrict__ partial) {
  __shared__ unsigned short Ks[128 * 64];      // 16KB, swzA staged K
  __shared__ unsigned short PVT[64][136];      // 17408B, V^T padded
  __shared__ unsigned short WL[8][16 * 128];   // 32KB: per-wave [q][k], rows 256B, XOR (q&7)<<4
  __shared__ float SUMS[8][128];               // 4KB  per-wave column partial sums
  __shared__ float RINV[128];                  // 512B reciprocal column totals
  __shared__ float kw2L[KWPER * 64];           // 2.5KB
  __shared__ float kwmL[KWPER * 64];           // 2.5KB
  int tid = threadIdx.x;
  int lane = tid & 63, wid = tid >> 6;
  int g = lane >> 4, c16 = lane & 15;
  int chunk = blockIdx.x, h = blockIdx.y, b = blockIdx.z;
  const size_t rowbase = (size_t)b * 128 * QKVN;
  int kq = tid >> 2, quarter = tid & 3;
  // ---- prologue: stage K (swzA), V^T (padded), kw tables; load Q frag ----
  {
    const unsigned short* srck = PQKV + rowbase + (size_t)kq * QKVN + H_ + h * HD_ + quarter * 16;
    ushort8 v0 = *(const ushort8*)srck;
    ushort8 v1 = *(const ushort8*)(srck + 8);
    *(ushort8*)&Ks[swzA(kq, quarter * 16)] = v0;
    *(ushort8*)&Ks[swzA(kq, quarter * 16 + 8)] = v1;
    const unsigned short* srcv = PQKV + rowbase + (size_t)kq * QKVN + 2 * H_ + h * HD_ + quarter * 16;
    ushort8 w0 = *(const ushort8*)srcv;
    ushort8 w1 = *(const ushort8*)(srcv + 8);
#pragma unroll
    for (int j = 0; j < 8; j++) PVT[quarter * 16 + j][kq] = w0[j];
#pragma unroll
    for (int j = 0; j < 8; j++) PVT[quarter * 16 + 8 + j][kq] = w1[j];
    for (int i = tid; i < KWPER * 64; i += 512) {
      int ki = i >> 6, d = i & 63;
      size_t gi = (size_t)(chunk * KWPER + ki) * H_ + h * HD_ + d;
      kw2L[i] = kw2s[gi];
      kwmL[i] = kwm[gi];
    }
  }
  // lane-private Q row (q = wid*16 + c16), d = g*8..g*8+7 and +32
  const unsigned short* qp = PQKV + rowbase + (size_t)(wid * 16 + c16) * QKVN + h * HD_;
  ushort8 qf0 = *(const ushort8*)(qp + g * 8);
  ushort8 qf1 = *(const ushort8*)(qp + 32 + g * 8);
  __syncthreads();
  // ---- loop-invariant K and V fragments into registers ----
  short8 kf[8][2];
#pragma unroll
  for (int t = 0; t < 8; t++)
#pragma unroll
    for (int s = 0; s < 2; s++)
      kf[t][s] = *(const short8*)&Ks[swzA(t * 16 + c16, s * 32 + g * 8)];
  short8 vf[4][4];
#pragma unroll
  for (int dt = 0; dt < 4; dt++)
#pragma unroll
    for (int s = 0; s < 4; s++)
      vf[dt][s] = *(const short8*)&PVT[dt * 16 + c16][s * 32 + g * 8];
  char* wbuf = (char*)&WL[wid][0];
  float accO[4][4] = {};
  for (int ki = 0; ki < KWPER; ki++) {
    // ---- build scaled-Q A-frags in registers ----
    const float* kp = &kw2L[ki * 64];
    short8 aA0, aA1;
    {
      float4 ka = *(const float4*)&kp[g * 8];
      float4 kb = *(const float4*)&kp[g * 8 + 4];
      float4 kc = *(const float4*)&kp[32 + g * 8];
      float4 kd = *(const float4*)&kp[32 + g * 8 + 4];
      union { unsigned u[4]; short8 v; } p0, p1;
      asm("v_cvt_pk_bf16_f32 %0, %1, %2" : "=v"(p0.u[0]) : "v"(b2f(qf0[0]) * ka.x), "v"(b2f(qf0[1]) * ka.y));
      asm("v_cvt_pk_bf16_f32 %0, %1, %2" : "=v"(p0.u[1]) : "v"(b2f(qf0[2]) * ka.z), "v"(b2f(qf0[3]) * ka.w));
      asm("v_cvt_pk_bf16_f32 %0, %1, %2" : "=v"(p0.u[2]) : "v"(b2f(qf0[4]) * kb.x), "v"(b2f(qf0[5]) * kb.y));
      asm("v_cvt_pk_bf16_f32 %0, %1, %2" : "=v"(p0.u[3]) : "v"(b2f(qf0[6]) * kb.z), "v"(b2f(qf0[7]) * kb.w));
      asm("v_cvt_pk_bf16_f32 %0, %1, %2" : "=v"(p1.u[0]) : "v"(b2f(qf1[0]) * kc.x), "v"(b2f(qf1[1]) * kc.y));
      asm("v_cvt_pk_bf16_f32 %0, %1, %2" : "=v"(p1.u[1]) : "v"(b2f(qf1[2]) * kc.z), "v"(b2f(qf1[3]) * kc.w));
      asm("v_cvt_pk_bf16_f32 %0, %1, %2" : "=v"(p1.u[2]) : "v"(b2f(qf1[4]) * kd.x), "v"(b2f(qf1[5]) * kd.y));
      asm("v_cvt_pk_bf16_f32 %0, %1, %2" : "=v"(p1.u[3]) : "v"(b2f(qf1[6]) * kd.z), "v"(b2f(qf1[7]) * kd.w));
      aA0 = p0.v; aA1 = p1.v;
    }
    // ---- QK^T + exp2 + pack; column partial sums over this strip's 16 q ----
    unsigned e[8][2];
    float s8v[8];
    __builtin_amdgcn_s_setprio(1);
#pragma unroll
    for (int t = 0; t < 8; t++) {
      f32x4 z = {0.f, 0.f, 0.f, 0.f};
      z = __builtin_amdgcn_mfma_f32_16x16x32_bf16(aA0, kf[t][0], z, 0, 0, 0);
      z = __builtin_amdgcn_mfma_f32_16x16x32_bf16(aA1, kf[t][1], z, 0, 0, 0);
      float e0 = __builtin_amdgcn_exp2f(z[0]);
      float e1 = __builtin_amdgcn_exp2f(z[1]);
      float e2 = __builtin_amdgcn_exp2f(z[2]);
      float e3 = __builtin_amdgcn_exp2f(z[3]);
      s8v[t] = (e0 + e1) + (e2 + e3);
      asm("v_cvt_pk_bf16_f32 %0, %1, %2" : "=v"(e[t][0]) : "v"(e0), "v"(e1));
      asm("v_cvt_pk_bf16_f32 %0, %1, %2" : "=v"(e[t][1]) : "v"(e2), "v"(e3));
    }
    __builtin_amdgcn_s_setprio(0);
#pragma unroll
    for (int t = 0; t < 8; t++) {
      s8v[t] += __shfl_xor(s8v[t], 16);
      s8v[t] += __shfl_xor(s8v[t], 32);
    }
    if (g == 0) {
#pragma unroll
      for (int t = 0; t < 8; t++) SUMS[wid][c16 + 16 * t] = s8v[t];
    }
    __syncthreads();
    if (tid < 128) {
      float tot = 0.f;
#pragma unroll
      for (int w = 0; w < 8; w++) tot += SUMS[w][tid];
      RINV[tid] = 1.0f / tot;
    }
    __syncthreads();
    // ---- normalize + write per-wave WL [q][k] (XOR (q&7)<<4) ----
    {
      int cb2 = c16 * 2;
      int qb = g * 4;
      int xb = (g & 1) * 4;
#pragma unroll
      for (int t = 0; t < 8; t++) {
        float ri = RINV[c16 + 16 * t];
        float w0 = b2f((unsigned short)(e[t][0] & 0xffffu)) * ri;
        float w1 = b2f((unsigned short)(e[t][0] >> 16)) * ri;
        float w2 = b2f((unsigned short)(e[t][1] & 0xffffu)) * ri;
        float w3 = b2f((unsigned short)(e[t][1] >> 16)) * ri;
        unsigned p01, p23;
        asm("v_cvt_pk_bf16_f32 %0, %1, %2" : "=v"(p01) : "v"(w0), "v"(w1));
        asm("v_cvt_pk_bf16_f32 %0, %1, %2" : "=v"(p23) : "v"(w2), "v"(w3));
        int tb = t * 32 + cb2;
        int a0 = ((qb + 0) * 256 + tb) ^ ((xb + 0) << 4);
        int a1 = ((qb + 1) * 256 + tb) ^ ((xb + 1) << 4);
        int a2 = ((qb + 2) * 256 + tb) ^ ((xb + 2) << 4);
        int a3 = ((qb + 3) * 256 + tb) ^ ((xb + 3) << 4);
        *(unsigned short*)(wbuf + a0) = (unsigned short)(p01 & 0xffffu);
        *(unsigned short*)(wbuf + a1) = (unsigned short)(p01 >> 16);
        *(unsigned short*)(wbuf + a2) = (unsigned short)(p23 & 0xffffu);
        *(unsigned short*)(wbuf + a3) = (unsigned short)(p23 >> 16);
      }
    }
    // ---- PV: A-frags from own WL, B = V regs ----
    short8 wf[4];
#pragma unroll
    for (int s = 0; s < 4; s++)
      wf[s] = *(const short8*)(wbuf + ((c16 * 256 + s * 64 + g * 16) ^ ((c16 & 7) << 4)));
    __builtin_amdgcn_s_setprio(1);
    f32x4 zz[4];
#pragma unroll
    for (int dt = 0; dt < 4; dt++) {
      f32x4 z = {0.f, 0.f, 0.f, 0.f};
#pragma unroll
      for (int s = 0; s < 4; s++)
        z = __builtin_amdgcn_mfma_f32_16x16x32_bf16(wf[s], vf[dt][s], z, 0, 0, 0);
      zz[dt] = z;
    }
    __builtin_amdgcn_s_setprio(0);
#pragma unroll
    for (int dt = 0; dt < 4; dt++) {
      float km = kwmL[ki * 64 + dt * 16 + c16];
#pragma unroll
      for (int rr = 0; rr < 4; rr++) accO[dt][rr] += zz[dt][rr] * km;
    }
  }
  float* dst = partial + (size_t)chunk * M_ * H_;
#pragma unroll
  for (int dt = 0; dt < 4; dt++)
#pragma unroll
    for (int rr = 0; rr < 4; rr++) {
      int q = wid * 16 + g * 4 + rr;
      dst[(size_t)(b * 128 + q) * H_ + h * HD_ + dt * 16 + c16] = accO[dt][rr];
    }
}

__global__ void k_reduce(const float* __restrict__ partial, unsigned short* __restrict__ ctxsum) {
  int i = (blockIdx.x * 256 + threadIdx.x) * 4;
  float4 s = *(const float4*)&partial[i];
#pragma unroll
  for (int c = 1; c < NCHUNK; c++) {
    float4 v = *(const float4*)&partial[(size_t)c * M_ * H_ + i];
    s.x += v.x; s.y += v.y; s.z += v.z; s.w += v.w;
  }
  uint2 o;
  o.x = (unsigned)f2b(s.x) | ((unsigned)f2b(s.y) << 16);
  o.y = (unsigned)f2b(s.z) | ((unsigned)f2b(s.w) << 16);
  *(uint2*)&ctxsum[i] = o;
}

// LayerNorm with fused up-proj split-K reduce + bias + residual
__launch_bounds__(256)
__global__ void k_ln2(const float* __restrict__ pUp, const float* __restrict__ bup,
                      const float* __restrict__ fusedF,
                      const float* __restrict__ gamma, const float* __restrict__ beta,
                      float* __restrict__ out) {
  __shared__ float red[8];
  int row = blockIdx.x, t = threadIdx.x;
  int lane = t & 63, wid = t >> 6;
  const size_t MN = (size_t)M_ * H_;
  const size_t rb = (size_t)row * H_;
  float v[3];
#pragma unroll
  for (int j = 0; j < 3; j++) {
    int c = t + j * 256;
    float x = pUp[rb + c] + pUp[MN + rb + c] + pUp[2 * MN + rb + c] + pUp[3 * MN + rb + c];
    v[j] = x + bup[c] + fusedF[rb + c];
  }
  float s = v[0] + v[1] + v[2];
#pragma unroll
  for (int off = 1; off < 64; off <<= 1) s += __shfl_xor(s, off);
  if (lane == 0) red[wid] = s;
  __syncthreads();
  float mu = (red[0] + red[1] + red[2] + red[3]) * (1.f / 768.f);
  float q = 0.f;
#pragma unroll
  for (int j = 0; j < 3; j++) { float d = v[j] - mu; q += d * d; }
#pragma unroll
  for (int off = 1; off < 64; off <<= 1) q += __shfl_xor(q, off);
  if (lane == 0) red[4 + wid] = q;
  __syncthreads();
  float var = (red[4] + red[5] + red[6] + red[7]) * (1.f / 768.f);
  float rstd = rsqrtf(var + 1e-12f);
#pragma unroll
  for (int j = 0; j < 3; j++) {
    int c = t + j * 256;
    out[rb + c] = gamma[c] * ((v[j] - mu) * rstd) + beta[c];
  }
}

// ---------------- launch ----------------

extern "C" void kernel_launch(void* const* d_in, const int* in_sizes, int n_in,
                              void* d_out, int out_size, void* d_ws, size_t ws_size,
                              hipStream_t stream) {
  const float* hidden = (const float*)d_in[0];
  const float* posk   = (const float*)d_in[1];
  const float* negk   = (const float*)d_in[2];
  const float* Wq     = (const float*)d_in[4];
  const float* Wk     = (const float*)d_in[5];
  const float* Wv     = (const float*)d_in[6];
  const float* Wo     = (const float*)d_in[7];
  const float* bo     = (const float*)d_in[8];
  const float* Wmlp   = (const float*)d_in[9];
  const float* bmlp   = (const float*)d_in[10];
  const float* Wdown  = (const float*)d_in[11];
  const float* bdown  = (const float*)d_in[12];
  const float* Wup    = (const float*)d_in[13];
  const float* bup    = (const float*)d_in[14];
  const float* gamma  = (const float*)d_in[15];
  const float* beta   = (const float*)d_in[16];

  char* ws = (char*)d_ws;
  size_t off = 0;
  auto alloc = [&](size_t bytes) -> void* {
    void* p = ws + off;
    off += (bytes + 255) & ~(size_t)255;
    return p;
  };
  unsigned short* hb     = (unsigned short*)alloc((size_t)M_ * H_ * 2);
  unsigned short* qkvT   = (unsigned short*)alloc((size_t)QKVN * H_ * 2);
  unsigned short* WoT    = (unsigned short*)alloc((size_t)H_ * H_ * 2);
  unsigned short* WdownT = (unsigned short*)alloc((size_t)I_ * H_ * 2);
  unsigned short* WupT   = (unsigned short*)alloc((size_t)H_ * I_ * 2);
  unsigned short* PQKV   = (unsigned short*)alloc((size_t)M_ * QKVN * 2);
  float* kw2s    = (float*)alloc((size_t)KW_ * H_ * 4);
  float* kwm     = (float*)alloc((size_t)KW_ * H_ * 4);
  float* c0      = (float*)alloc((size_t)H_ * 4);
  float* partial = (float*)alloc((size_t)NCHUNK * M_ * H_ * 4);  // aliased by GEMM split-K partials
  unsigned short* ctxsum = (unsigned short*)alloc((size_t)M_ * H_ * 2);
  float* fusedF  = (float*)alloc((size_t)M_ * H_ * 4);
  unsigned short* fusedB = (unsigned short*)alloc((size_t)M_ * H_ * 2);
  unsigned short* downB  = (unsigned short*)alloc((size_t)M_ * I_ * 2);

  k_prep<<<dim3(96, 24, 7), 256, 0, stream>>>(hidden, Wq, Wk, Wv, Wo, Wdown, Wup,
                                              posk, negk, Wmlp, bmlp, bo,
                                              hb, qkvT, WoT, WdownT, WupT, kw2s, kwm, c0);
  // QKV projection: split-K x2 -> f32 partial -> bf16 PQKV
  k_gemm_sk<<<dim3(18, 8, 2), 256, 0, stream>>>(hb, qkvT, M_, QKVN, H_, 384, partial);
  k_red<2, 0><<<2304, 256, 0, stream>>>(partial, nullptr, nullptr, PQKV, QKVN);
  k_attn<<<dim3(NCHUNK, NH_, B_), 512, 0, stream>>>(PQKV, kw2s, kwm, partial);
  k_reduce<<<768, 256, 0, stream>>>(partial, ctxsum);
  // Wo: split-K x2 ; reduce adds c0 (= sum(Wmlp)*bo + bmlp)
  k_gemm_sk<<<dim3(6, 8, 2), 256, 0, stream>>>(ctxsum, WoT, M_, H_, H_, 384, partial);
  k_red<2, 1><<<768, 256, 0, stream>>>(partial, c0, fusedF, fusedB, H_);
  // down-proj: fused gelu epilogue
  k_gemm_bt<2><<<dim3(24, 8), 256, 0, stream>>>(fusedB, WdownT, M_, I_, H_, nullptr, downB, bdown, nullptr);
  // up-proj: split-K x4 ; reduce + bias + residual + LN fused into k_ln2
  k_gemm_sk<<<dim3(6, 8, 4), 256, 0, stream>>>(downB, WupT, M_, H_, I_, 768, partial);
  k_ln2<<<M_, 256, 0, stream>>>(partial, bup, fusedF, gamma, beta, (float*)d_out);
}